// Round 2
// baseline (188.521 us; speedup 1.0000x reference)
//
#include <hip/hip_runtime.h>

#define NB 1024
#define LL 4096
#define PP 8192
#define FN 4096   // complex FFT length = PP/2 (real-packed Hilbert)

#define PIF 3.14159265358979323846f

__device__ __forceinline__ float2 cadd(float2 a, float2 b){ return make_float2(a.x+b.x, a.y+b.y); }
__device__ __forceinline__ float2 csub(float2 a, float2 b){ return make_float2(a.x-b.x, a.y-b.y); }
__device__ __forceinline__ float2 cmul(float2 a, float2 b){ return make_float2(a.x*b.x - a.y*b.y, a.x*b.y + a.y*b.x); }

// LDS bank swizzle on the float2 index: fold bits [7:4] into [3:0] (bijective).
__device__ __forceinline__ int SW(int p){ return p ^ ((p >> 4) & 15); }

// base-4 digit reversal of a 12-bit index (6 digits) — the DIF output permutation.
__device__ __forceinline__ int rho(int k){
    return ((k & 3) << 10) | (((k >> 2) & 3) << 8) | (((k >> 4) & 3) << 6)
         | (((k >> 6) & 3) << 4) | (((k >> 8) & 3) << 2) | ((k >> 10) & 3);
}

// constant rotations exp(-i*pi*a/8), a=1..3 (forward); conj for inverse
__device__ __forceinline__ float2 CFc(int a){
    return (a==1) ? make_float2(0.92387953251f, -0.38268343236f)
         : (a==2) ? make_float2(0.70710678119f, -0.70710678119f)
         :          make_float2(0.38268343236f, -0.92387953251f);
}
__device__ __forceinline__ float2 CIc(int a){ float2 c = CFc(a); return make_float2(c.x, -c.y); }

// ---- register radix-4 butterflies (stride S within a 16-element local array) ----
template<int S>
__device__ __forceinline__ void bf4f(float2* x, float2 E){
    float2 E2 = cmul(E,E), E3 = cmul(E2,E);
    float2 t0 = cadd(x[0],x[2*S]), t1 = cadd(x[S],x[3*S]);
    float2 t2 = csub(x[0],x[2*S]), t3 = csub(x[S],x[3*S]);
    x[0]   = cadd(t0,t1);
    x[2*S] = cmul(csub(t0,t1), E2);
    x[S]   = cmul(make_float2(t2.x + t3.y, t2.y - t3.x), E);   // (t2 - i*t3)*E
    x[3*S] = cmul(make_float2(t2.x - t3.y, t2.y + t3.x), E3);  // (t2 + i*t3)*E3
}
template<int S>
__device__ __forceinline__ void bf4f_nt(float2* x){
    float2 t0 = cadd(x[0],x[2*S]), t1 = cadd(x[S],x[3*S]);
    float2 t2 = csub(x[0],x[2*S]), t3 = csub(x[S],x[3*S]);
    x[0]   = cadd(t0,t1);
    x[2*S] = csub(t0,t1);
    x[S]   = make_float2(t2.x + t3.y, t2.y - t3.x);
    x[3*S] = make_float2(t2.x - t3.y, t2.y + t3.x);
}
template<int S>
__device__ __forceinline__ void bf4i(float2* x, float2 E){
    float2 E2 = cmul(E,E), E3 = cmul(E2,E);
    float2 z0 = x[0], z1 = cmul(x[S],E), z2 = cmul(x[2*S],E2), z3 = cmul(x[3*S],E3);
    float2 s0 = cadd(z0,z2), s1 = cadd(z1,z3);
    float2 s2 = csub(z0,z2), s3 = csub(z1,z3);
    x[0]   = cadd(s0,s1);
    x[2*S] = csub(s0,s1);
    x[S]   = make_float2(s2.x - s3.y, s2.y + s3.x);   // s2 + i*s3
    x[3*S] = make_float2(s2.x + s3.y, s2.y - s3.x);   // s2 - i*s3
}
template<int S>
__device__ __forceinline__ void bf4i_nt(float2* x){
    float2 z0 = x[0], z1 = x[S], z2 = x[2*S], z3 = x[3*S];
    float2 s0 = cadd(z0,z2), s1 = cadd(z1,z3);
    float2 s2 = csub(z0,z2), s3 = csub(z1,z3);
    x[0]   = cadd(s0,s1);
    x[2*S] = csub(s0,s1);
    x[S]   = make_float2(s2.x - s3.y, s2.y + s3.x);
    x[3*S] = make_float2(s2.x + s3.y, s2.y - s3.x);
}

// ---- Hilbert middle step, in DIF-scrambled position space ----
// buf[SW(rho(k))] = Z[k] -> Z'[k];  Z'[k] = (u*conj(W) - v*W)/(2*FN),
// W = e^{-i*pi*k/FN}, u = Z[k]+conj(Z[FN-k]), v = Z[k]-conj(Z[FN-k]); Z'[0]=0.
__device__ __forceinline__ void hilbert_mid(float2* buf, int tid){
    const float s = 1.0f/(2.0f*(float)FN);
#pragma unroll
    for (int m = 0; m < 8; m++){
        int k = ((tid & 31) << 6) | ((tid >> 5) << 3) | m;
        if (k == 0){
            buf[0] = make_float2(0.0f, 0.0f);                 // rho(0)=0, SW(0)=0
            int p = SW(2);                                    // rho(2048)=2, self-paired
            float2 Z = buf[p];
            buf[p] = make_float2(-2.0f*s*Z.y, 2.0f*s*Z.x);
        } else {
            int pk = SW(rho(k));
            int pj = SW(rho(FN - k));
            float2 Zk = buf[pk];
            float2 Zj = buf[pj];
            float ux = Zk.x + Zj.x, uy = Zk.y - Zj.y;
            float vx = Zk.x - Zj.x, vy = Zk.y + Zj.y;
            float sn, cn; __sincosf((PIF/(float)FN) * (float)k, &sn, &cn);  // conj(W)=(cn,sn)
            float2 zk, zj;
            zk.x = s * ((ux*cn - uy*sn) - (vx*cn + vy*sn));
            zk.y = s * ((ux*sn + uy*cn) + (vx*sn - vy*cn));
            float u2x = ux,  u2y = -uy;
            float v2x = -vx, v2y = vy;
            zj.x = s * ((v2x*cn - v2y*sn) - (u2x*cn + u2y*sn));
            zj.y = s * ((v2x*sn + v2y*cn) + (u2x*sn - u2y*cn));
            buf[pk] = zk;
            buf[pj] = zj;
        }
    }
}

__global__ __launch_bounds__(256, 4) void k_all(
    const float* __restrict__ g_start,
    const float* __restrict__ g_end,
    const float* __restrict__ g_std,
    const float* __restrict__ g_low,
    const float* __restrict__ g_up,
    const int*   __restrict__ g_win,
    const float* __restrict__ g_scale,
    const float* __restrict__ g_noise,
    const float* __restrict__ g_omit,
    const float* __restrict__ g_ppm,
    const float* __restrict__ g_ppmr,
    float* __restrict__ g_out)
{
    __shared__ float2 buf[FN];          // 32 KB
    float* bf  = (float*)buf;           // 8192 floats
#define CSI(t) ((t) + ((t) >> 5))
    float* cs  = bf;                    // CSI(0..4096) -> 0..4224
    float* tmp = bf + 4226;             // 8 floats (wave partials)
    float* shv = bf + 4234;             // 2 floats

    const int n    = blockIdx.x;
    const int tid  = threadIdx.x;
    const int lane = tid & 63;
    const int wid  = tid >> 6;          // 4 waves / block
    const float st = g_start[n];
    const float en = g_end[n];
    const float sd = g_std[n];
    const float lo = g_low[n];
    const float up = g_up[n];
    const int   w  = g_win[n];
    const float inv_nm1 = 1.0f / (float)(LL - 1);

    // ---- load 16 fp32 noise steps/thread ----
    float v[16];
    {
        const float4* p = (const float4*)(g_noise + (size_t)n * LL) + (size_t)tid * 4;
#pragma unroll
        for (int q = 0; q < 4; q++) {
            float4 t4 = p[q];
            v[4*q+0] = t4.x; v[4*q+1] = t4.y; v[4*q+2] = t4.z; v[4*q+3] = t4.w;
        }
    }
#pragma unroll
    for (int k = 0; k < 16; k++) v[k] = sd * (v[k] - 0.5f);

    // ---- scan #1 (rand = inclusive cumsum) ----
    float run = 0.0f;
#pragma unroll
    for (int k = 0; k < 16; k++) { run += v[k]; v[k] = run; }
    float ws = run;
#pragma unroll
    for (int off = 1; off < 64; off <<= 1) { float t = __shfl_up(ws, off); if (lane >= off) ws += t; }
    if (lane == 63) tmp[wid] = ws;
    if (tid == 0)   shv[0] = v[0];                 // rand[0]
    __syncthreads();
    float w0 = tmp[0], w1 = tmp[1], w2s = tmp[2], w3 = tmp[3];
    const float rT = w0 + w1 + w2s + w3;           // rand[L-1]
    const float r0 = shv[0];
    float base = (wid > 0 ? w0 : 0.0f) + (wid > 1 ? w1 : 0.0f) + (wid > 2 ? w2s : 0.0f);
    float excl = base + ws - run;
    __syncthreads();

    // ---- detrend walk, min/max ----
    float del[16];
    float mx = -INFINITY, mn = INFINITY;
#pragma unroll
    for (int k = 0; k < 16; k++) {
        int t = tid * 16 + k;
        float d = (excl + v[k]) - (r0 + (rT - r0) * ((float)t * inv_nm1));
        del[k] = d;
        mx = fmaxf(mx, d); mn = fminf(mn, d);
    }
#pragma unroll
    for (int off = 32; off > 0; off >>= 1) {
        mx = fmaxf(mx, __shfl_xor(mx, off));
        mn = fminf(mn, __shfl_xor(mn, off));
    }
    if (lane == 0) { tmp[wid] = mx; tmp[4 + wid] = mn; }
    __syncthreads();
    mx = fmaxf(fmaxf(tmp[0], tmp[1]), fmaxf(tmp[2], tmp[3]));
    mn = fminf(fminf(tmp[4], tmp[5]), fminf(tmp[6], tmp[7]));
    __syncthreads();

    const float qs = fmaxf(1.0f, (mx - mn) / (up - lo));

    // ---- squeeze + reflect + trend -> walk values ----
    float wv[16];
#pragma unroll
    for (int k = 0; k < 16; k++) {
        int t = tid * 16 + k;
        float tr  = st + (en - st) * ((float)t * inv_nm1);
        float ub  = up - tr;
        float lb2 = lo - tr;
        float d = del[k] / qs;
        float over = d - ub;
        d = (over >= 0.0f) ? (ub - over) : d;
        float under = lb2 - d;
        d = (under >= 0.0f) ? (lb2 + under) : d;
        wv[k] = tr + d;
    }

    // ---- scan #2: exclusive cumsum of walk -> cs[CSI(0..LL)] ----
    run = 0.0f;
#pragma unroll
    for (int k = 0; k < 16; k++) { run += wv[k]; wv[k] = run; }
    ws = run;
#pragma unroll
    for (int off = 1; off < 64; off <<= 1) { float t = __shfl_up(ws, off); if (lane >= off) ws += t; }
    if (lane == 63) tmp[wid] = ws;
    __syncthreads();
    w0 = tmp[0]; w1 = tmp[1]; w2s = tmp[2]; w3 = tmp[3];
    const float grand2 = w0 + w1 + w2s + w3;
    base = (wid > 0 ? w0 : 0.0f) + (wid > 1 ? w1 : 0.0f) + (wid > 2 ? w2s : 0.0f);
    float excl2 = base + ws - run;
#pragma unroll
    for (int k = 0; k < 16; k++) {
        int t = tid * 16 + k;
        cs[CSI(t)] = excl2 + ((k == 0) ? 0.0f : wv[k - 1]);
    }
    if (tid == 255) cs[CSI(LL)] = grand2;
    __syncthreads();

    // ---- box smooth (cyclic t: conflict-free cs reads) ----
    const int wh = w / 2;
    const float invw = 1.0f / (float)w;
    float bvals[16];
#pragma unroll
    for (int k = 0; k < 16; k++) {
        int t  = tid + 256 * k;
        int li = t - wh;
        int hi = li + w;
        li = (li < 0) ? 0 : li;
        hi = (hi > LL) ? LL : hi;
        bvals[k] = (cs[CSI(hi)] - cs[CSI(li)]) * invw;
    }
    if (tid == 0)   shv[0] = bvals[0];     // b[0]
    if (tid == 255) shv[1] = bvals[15];    // b[L-1]
    __syncthreads();
    const float b0 = shv[0], bL = shv[1];

    // ---- detrend #2 + absmax-normalize ----
    float am = 0.0f;
#pragma unroll
    for (int k = 0; k < 16; k++) {
        int t = tid + 256 * k;
        bvals[k] -= b0 + (bL - b0) * ((float)t * inv_nm1);
        am = fmaxf(am, fabsf(bvals[k]));
    }
#pragma unroll
    for (int off = 32; off > 0; off >>= 1) am = fmaxf(am, __shfl_xor(am, off));
    if (lane == 0) tmp[wid] = am;
    __syncthreads();
    float denom = fmaxf(fmaxf(tmp[0], tmp[1]), fmaxf(tmp[2], tmp[3]));
    denom = (denom == 0.0f) ? 1.0f : denom;
    const float fac = g_omit[n] * g_scale[n] / denom;

    // ---- stash bb row at bf[t] (overwrites cs; all cs reads completed) ----
#pragma unroll
    for (int k = 0; k < 16; k++) {
        int t = tid + 256 * k;
        bf[t] = bvals[k] * fac;
    }
    __syncthreads();

    // ---- interp bb onto ppm axis, DIRECTLY into the pass-A register tile ----
    // X[a+4b] = (x[2p], x[2p+1]), p = tid + 256a + 1024b.  Real output planes
    // are written here too (Re(analytic) == x exactly).
    const float xlo = g_ppmr[0];
    const float xhi = g_ppmr[1];
    const float posmul = (float)(LL - 1) / (xhi - xlo);
    const size_t base1 = (size_t)NB * 2 * PP + (size_t)n * 2 * PP;  // raw
    const size_t base0 = (size_t)n * 2 * PP;                        // flipped

    auto interp1 = [&](float x) -> float {
        if (x < xlo || x > xhi) return 0.0f;
        float pos = (x - xlo) * posmul;
        int idx = (int)floorf(pos);
        idx = (idx < 0) ? 0 : ((idx > LL - 2) ? (LL - 2) : idx);
        float fr = pos - (float)idx;
        float s0 = bf[idx], s1 = bf[idx + 1];
        return s0 + (s1 - s0) * fr;
    };

    float2 X[16];
#pragma unroll
    for (int b = 0; b < 4; b++)
#pragma unroll
    for (int a = 0; a < 4; a++) {
        int p = tid + 256 * a + 1024 * b;
        float2 pm = *(const float2*)(g_ppm + 2 * p);
        float re0 = interp1(pm.x);
        float re1 = interp1(pm.y);
        X[a + 4 * b] = make_float2(re0, re1);
        *(float2*)(g_out + base1 + 2 * p)          = make_float2(re0, re1);
        *(float2*)(g_out + base0 + PP - 2 - 2 * p) = make_float2(re1, re0);
    }
    __syncthreads();   // all bb reads complete (buf stores below overwrite bf)

    // ===== forward FFT: 3 fused radix-16 passes (radix-4 x2 in registers) =====
    // pass A: stages H=1024 then H=256 (X already loaded)
    {
        float sn, cn;
        __sincosf((-PIF / 2048.0f) * (float)tid, &sn, &cn);
        float2 Eb = make_float2(cn, sn);                 // angle -(pi/2048)(tid+256a) = base - (pi/8)a
#pragma unroll
        for (int a = 0; a < 4; a++) {
            float2 E = (a == 0) ? Eb : cmul(Eb, CFc(a));
            bf4f<4>(&X[a], E);
        }
        __sincosf((-PIF / 512.0f) * (float)tid, &sn, &cn);
        float2 E = make_float2(cn, sn);                  // j = tid for all b
#pragma unroll
        for (int b = 0; b < 4; b++) bf4f<1>(&X[4 * b], E);
#pragma unroll
        for (int b = 0; b < 4; b++)
#pragma unroll
        for (int a = 0; a < 4; a++)
            buf[SW(tid + 256 * a + 1024 * b)] = X[a + 4 * b];
    }
    __syncthreads();

    // pass B: stages H=64 then H=16
    const int u  = tid >> 4;
    const int lw = tid & 15;
    const int pb = u * 256 + lw;
    {
#pragma unroll
        for (int b = 0; b < 4; b++)
#pragma unroll
        for (int a = 0; a < 4; a++)
            X[a + 4 * b] = buf[SW(pb + 64 * b + 16 * a)];
        float sn, cn;
        __sincosf((-PIF / 128.0f) * (float)lw, &sn, &cn);
        float2 Eb = make_float2(cn, sn);                 // angle -(pi/128)(16a+lw)
#pragma unroll
        for (int a = 0; a < 4; a++) {
            float2 E = (a == 0) ? Eb : cmul(Eb, CFc(a));
            bf4f<4>(&X[a], E);
        }
        __sincosf((-PIF / 32.0f) * (float)lw, &sn, &cn);
        float2 E = make_float2(cn, sn);                  // j = lw for all b
#pragma unroll
        for (int b = 0; b < 4; b++) bf4f<1>(&X[4 * b], E);
#pragma unroll
        for (int b = 0; b < 4; b++)
#pragma unroll
        for (int a = 0; a < 4; a++)
            buf[SW(pb + 64 * b + 16 * a)] = X[a + 4 * b];
    }
    __syncthreads();

    // pass C: stages H=4 then H=1 (twiddles are pure constants)
    {
#pragma unroll
        for (int c = 0; c < 16; c++) X[c] = buf[SW(16 * tid + c)];
        bf4f_nt<4>(&X[0]);
#pragma unroll
        for (int a = 1; a < 4; a++) bf4f<4>(&X[a], CFc(a));
#pragma unroll
        for (int b = 0; b < 4; b++) bf4f_nt<1>(&X[4 * b]);
#pragma unroll
        for (int c = 0; c < 16; c++) buf[SW(16 * tid + c)] = X[c];
    }
    __syncthreads();

    // ===== Hilbert pair-fix (unpack + filter + repack + 1/(2N)) =====
    hilbert_mid(buf, tid);
    __syncthreads();

    // ===== inverse FFT: 3 fused passes =====
    // pass C': stages H=1 then H=4
    {
#pragma unroll
        for (int c = 0; c < 16; c++) X[c] = buf[SW(16 * tid + c)];
#pragma unroll
        for (int b = 0; b < 4; b++) bf4i_nt<1>(&X[4 * b]);
        bf4i_nt<4>(&X[0]);
#pragma unroll
        for (int a = 1; a < 4; a++) bf4i<4>(&X[a], CIc(a));
#pragma unroll
        for (int c = 0; c < 16; c++) buf[SW(16 * tid + c)] = X[c];
    }
    __syncthreads();

    // pass B': stages H=16 then H=64
    {
#pragma unroll
        for (int b = 0; b < 4; b++)
#pragma unroll
        for (int a = 0; a < 4; a++)
            X[a + 4 * b] = buf[SW(pb + 64 * b + 16 * a)];
        float sn, cn;
        __sincosf((PIF / 32.0f) * (float)lw, &sn, &cn);
        float2 E = make_float2(cn, sn);
#pragma unroll
        for (int b = 0; b < 4; b++) bf4i<1>(&X[4 * b], E);
        __sincosf((PIF / 128.0f) * (float)lw, &sn, &cn);
        float2 Eb = make_float2(cn, sn);
#pragma unroll
        for (int a = 0; a < 4; a++) {
            float2 Ea = (a == 0) ? Eb : cmul(Eb, CIc(a));
            bf4i<4>(&X[a], Ea);
        }
#pragma unroll
        for (int b = 0; b < 4; b++)
#pragma unroll
        for (int a = 0; a < 4; a++)
            buf[SW(pb + 64 * b + 16 * a)] = X[a + 4 * b];
    }
    __syncthreads();

    // pass A': stages H=256 then H=1024; final values go straight to global
    {
#pragma unroll
        for (int b = 0; b < 4; b++)
#pragma unroll
        for (int a = 0; a < 4; a++)
            X[a + 4 * b] = buf[SW(tid + 256 * a + 1024 * b)];
        float sn, cn;
        __sincosf((PIF / 512.0f) * (float)tid, &sn, &cn);
        float2 E = make_float2(cn, sn);
#pragma unroll
        for (int b = 0; b < 4; b++) bf4i<1>(&X[4 * b], E);
        __sincosf((PIF / 2048.0f) * (float)tid, &sn, &cn);
        float2 Eb = make_float2(cn, sn);
#pragma unroll
        for (int a = 0; a < 4; a++) {
            float2 Ea = (a == 0) ? Eb : cmul(Eb, CIc(a));
            bf4i<4>(&X[a], Ea);
        }
        // X[a+4b] = (Hx[2p], Hx[2p+1]), p = tid + 256a + 1024b
#pragma unroll
        for (int b = 0; b < 4; b++)
#pragma unroll
        for (int a = 0; a < 4; a++) {
            int p = tid + 256 * a + 1024 * b;
            float2 vv = X[a + 4 * b];
            *(float2*)(g_out + base1 + PP + 2 * p)         = vv;                        // raw imag
            *(float2*)(g_out + base0 + 2 * PP - 2 - 2 * p) = make_float2(vv.y, vv.x);   // flipped imag
        }
    }
}

extern "C" void kernel_launch(void* const* d_in, const int* in_sizes, int n_in,
                              void* d_out, int out_size, void* d_ws, size_t ws_size,
                              hipStream_t stream)
{
    const float* start = (const float*)d_in[0];
    const float* end_  = (const float*)d_in[1];
    const float* stdv  = (const float*)d_in[2];
    const float* lowb  = (const float*)d_in[3];
    const float* upb   = (const float*)d_in[4];
    const int*   win   = (const int*)d_in[5];
    const float* scl   = (const float*)d_in[6];
    const float* noise = (const float*)d_in[7];
    const float* omit  = (const float*)d_in[8];
    const float* ppm   = (const float*)d_in[9];
    const float* ppmr  = (const float*)d_in[10];
    float* out = (float*)d_out;

    hipLaunchKernelGGL(k_all, dim3(NB), dim3(256), 0, stream,
                       start, end_, stdv, lowb, upb, win, scl, noise, omit,
                       ppm, ppmr, out);
}

// Round 3
// 183.876 us; speedup vs baseline: 1.0253x; 1.0253x over previous
//
#include <hip/hip_runtime.h>

#define NB 1024
#define LL 4096
#define PP 8192
#define FN 4096            // complex FFT length = PP/2 (real-packed Hilbert)
#define FNP (FN + FN/16)   // padded float2 count: 4352 (34 KB LDS)

#define PIF 3.14159265358979323846f

__device__ __forceinline__ float2 cadd(float2 a, float2 b){ return make_float2(a.x+b.x, a.y+b.y); }
__device__ __forceinline__ float2 csub(float2 a, float2 b){ return make_float2(a.x-b.x, a.y-b.y); }
__device__ __forceinline__ float2 cmul(float2 a, float2 b){ return make_float2(a.x*b.x - a.y*b.y, a.x*b.y + a.y*b.x); }

// additive LDS pad on the float2 index: bijective, and PH(p + c) = PH(p) + c'
// for the pass-structured c (disjoint bit fields) -> compile-time ds offsets.
__device__ __forceinline__ int PH(int p){ return p + (p >> 4); }

// base-4 digit reversal of a 12-bit index (6 digits) — the DIF output permutation.
__device__ __forceinline__ int rho(int k){
    return ((k & 3) << 10) | (((k >> 2) & 3) << 8) | (((k >> 4) & 3) << 6)
         | (((k >> 6) & 3) << 4) | (((k >> 8) & 3) << 2) | ((k >> 10) & 3);
}

// constant rotations exp(-i*pi*a/8), a=1..3 (forward); conj for inverse
__device__ __forceinline__ float2 CFc(int a){
    return (a==1) ? make_float2(0.92387953251f, -0.38268343236f)
         : (a==2) ? make_float2(0.70710678119f, -0.70710678119f)
         :          make_float2(0.38268343236f, -0.92387953251f);
}
__device__ __forceinline__ float2 CIc(int a){ float2 c = CFc(a); return make_float2(c.x, -c.y); }

// ---- register radix-4 butterflies (stride S within a 16-element local array) ----
template<int S>
__device__ __forceinline__ void bf4f(float2* x, float2 E){
    float2 E2 = cmul(E,E), E3 = cmul(E2,E);
    float2 t0 = cadd(x[0],x[2*S]), t1 = cadd(x[S],x[3*S]);
    float2 t2 = csub(x[0],x[2*S]), t3 = csub(x[S],x[3*S]);
    x[0]   = cadd(t0,t1);
    x[2*S] = cmul(csub(t0,t1), E2);
    x[S]   = cmul(make_float2(t2.x + t3.y, t2.y - t3.x), E);   // (t2 - i*t3)*E
    x[3*S] = cmul(make_float2(t2.x - t3.y, t2.y + t3.x), E3);  // (t2 + i*t3)*E3
}
template<int S>
__device__ __forceinline__ void bf4f_nt(float2* x){
    float2 t0 = cadd(x[0],x[2*S]), t1 = cadd(x[S],x[3*S]);
    float2 t2 = csub(x[0],x[2*S]), t3 = csub(x[S],x[3*S]);
    x[0]   = cadd(t0,t1);
    x[2*S] = csub(t0,t1);
    x[S]   = make_float2(t2.x + t3.y, t2.y - t3.x);
    x[3*S] = make_float2(t2.x - t3.y, t2.y + t3.x);
}
template<int S>
__device__ __forceinline__ void bf4i(float2* x, float2 E){
    float2 E2 = cmul(E,E), E3 = cmul(E2,E);
    float2 z0 = x[0], z1 = cmul(x[S],E), z2 = cmul(x[2*S],E2), z3 = cmul(x[3*S],E3);
    float2 s0 = cadd(z0,z2), s1 = cadd(z1,z3);
    float2 s2 = csub(z0,z2), s3 = csub(z1,z3);
    x[0]   = cadd(s0,s1);
    x[2*S] = csub(s0,s1);
    x[S]   = make_float2(s2.x - s3.y, s2.y + s3.x);   // s2 + i*s3
    x[3*S] = make_float2(s2.x + s3.y, s2.y - s3.x);   // s2 - i*s3
}
template<int S>
__device__ __forceinline__ void bf4i_nt(float2* x){
    float2 z0 = x[0], z1 = x[S], z2 = x[2*S], z3 = x[3*S];
    float2 s0 = cadd(z0,z2), s1 = cadd(z1,z3);
    float2 s2 = csub(z0,z2), s3 = csub(z1,z3);
    x[0]   = cadd(s0,s1);
    x[2*S] = csub(s0,s1);
    x[S]   = make_float2(s2.x - s3.y, s2.y + s3.x);
    x[3*S] = make_float2(s2.x + s3.y, s2.y - s3.x);
}

// ---- Hilbert middle step, in DIF-scrambled position space ----
// buf[PH(rho(k))] = Z[k] -> Z'[k];  Z'[k] = (u*conj(W) - v*W)/(2*FN),
// W = e^{-i*pi*k/FN}, u = Z[k]+conj(Z[FN-k]), v = Z[k]-conj(Z[FN-k]); Z'[0]=0.
__device__ __forceinline__ void hilbert_mid(float2* buf, int tid){
    const float s = 1.0f/(2.0f*(float)FN);
#pragma unroll
    for (int m = 0; m < 8; m++){
        int k = ((tid & 31) << 6) | ((tid >> 5) << 3) | m;
        if (k == 0){
            buf[0] = make_float2(0.0f, 0.0f);                 // rho(0)=0, PH(0)=0
            float2 Z = buf[2];                                // rho(2048)=2, PH(2)=2, self-paired
            buf[2] = make_float2(-2.0f*s*Z.y, 2.0f*s*Z.x);
        } else {
            int pk = PH(rho(k));
            int pj = PH(rho(FN - k));
            float2 Zk = buf[pk];
            float2 Zj = buf[pj];
            float ux = Zk.x + Zj.x, uy = Zk.y - Zj.y;
            float vx = Zk.x - Zj.x, vy = Zk.y + Zj.y;
            float sn, cn; __sincosf((PIF/(float)FN) * (float)k, &sn, &cn);  // conj(W)=(cn,sn)
            float2 zk, zj;
            zk.x = s * ((ux*cn - uy*sn) - (vx*cn + vy*sn));
            zk.y = s * ((ux*sn + uy*cn) + (vx*sn - vy*cn));
            float u2x = ux,  u2y = -uy;
            float v2x = -vx, v2y = vy;
            zj.x = s * ((v2x*cn - v2y*sn) - (u2x*cn + u2y*sn));
            zj.y = s * ((v2x*sn + v2y*cn) + (u2x*sn - u2y*cn));
            buf[pk] = zk;
            buf[pj] = zj;
        }
    }
}

__global__ __launch_bounds__(256, 4) void k_all(
    const float* __restrict__ g_start,
    const float* __restrict__ g_end,
    const float* __restrict__ g_std,
    const float* __restrict__ g_low,
    const float* __restrict__ g_up,
    const int*   __restrict__ g_win,
    const float* __restrict__ g_scale,
    const float* __restrict__ g_noise,
    const float* __restrict__ g_omit,
    const float* __restrict__ g_ppm,
    const float* __restrict__ g_ppmr,
    float* __restrict__ g_out)
{
    __shared__ float2 buf[FNP];         // 34 KB -> 4 blocks/CU
    float* bf  = (float*)buf;           // 8704 floats
#define CSI(t) ((t) + ((t) >> 5))
    float* cs  = bf;                    // CSI(0..4096) -> 0..4224
    float* tmp = bf + 4226;             // 8 floats (wave partials)
    float* shv = bf + 4234;             // 2 floats

    const int n    = blockIdx.x;
    const int tid  = threadIdx.x;
    const int lane = tid & 63;
    const int wid  = tid >> 6;          // 4 waves / block
    const float st = g_start[n];
    const float en = g_end[n];
    const float sd = g_std[n];
    const float lo = g_low[n];
    const float up = g_up[n];
    const int   w  = g_win[n];
    const float inv_nm1 = 1.0f / (float)(LL - 1);

    // ---- single in-place 16-float pre-FFT array (v/del/wv/bvals lifetimes are
    // strictly sequential -> one register array keeps peak VGPR low) ----
    float r[16];
    {
        const float4* p = (const float4*)(g_noise + (size_t)n * LL) + (size_t)tid * 4;
#pragma unroll
        for (int q = 0; q < 4; q++) {
            float4 t4 = p[q];
            r[4*q+0] = t4.x; r[4*q+1] = t4.y; r[4*q+2] = t4.z; r[4*q+3] = t4.w;
        }
    }
#pragma unroll
    for (int k = 0; k < 16; k++) r[k] = sd * (r[k] - 0.5f);

    // ---- scan #1 (rand = inclusive cumsum) ----
    float run = 0.0f;
#pragma unroll
    for (int k = 0; k < 16; k++) { run += r[k]; r[k] = run; }
    float ws = run;
#pragma unroll
    for (int off = 1; off < 64; off <<= 1) { float t = __shfl_up(ws, off); if (lane >= off) ws += t; }
    if (lane == 63) tmp[wid] = ws;
    if (tid == 0)   shv[0] = r[0];                 // rand[0]
    __syncthreads();
    float w0 = tmp[0], w1 = tmp[1], w2s = tmp[2], w3 = tmp[3];
    const float rT = w0 + w1 + w2s + w3;           // rand[L-1]
    const float r0 = shv[0];
    float base = (wid > 0 ? w0 : 0.0f) + (wid > 1 ? w1 : 0.0f) + (wid > 2 ? w2s : 0.0f);
    float excl = base + ws - run;
    __syncthreads();

    // ---- detrend walk (in place), min/max ----
    float mx = -INFINITY, mn = INFINITY;
#pragma unroll
    for (int k = 0; k < 16; k++) {
        int t = tid * 16 + k;
        float d = (excl + r[k]) - (r0 + (rT - r0) * ((float)t * inv_nm1));
        r[k] = d;
        mx = fmaxf(mx, d); mn = fminf(mn, d);
    }
#pragma unroll
    for (int off = 32; off > 0; off >>= 1) {
        mx = fmaxf(mx, __shfl_xor(mx, off));
        mn = fminf(mn, __shfl_xor(mn, off));
    }
    if (lane == 0) { tmp[wid] = mx; tmp[4 + wid] = mn; }
    __syncthreads();
    mx = fmaxf(fmaxf(tmp[0], tmp[1]), fmaxf(tmp[2], tmp[3]));
    mn = fminf(fminf(tmp[4], tmp[5]), fminf(tmp[6], tmp[7]));
    __syncthreads();

    const float qs = fmaxf(1.0f, (mx - mn) / (up - lo));

    // ---- squeeze + reflect + trend -> walk values (in place) ----
#pragma unroll
    for (int k = 0; k < 16; k++) {
        int t = tid * 16 + k;
        float tr  = st + (en - st) * ((float)t * inv_nm1);
        float ub  = up - tr;
        float lb2 = lo - tr;
        float d = r[k] / qs;
        float over = d - ub;
        d = (over >= 0.0f) ? (ub - over) : d;
        float under = lb2 - d;
        d = (under >= 0.0f) ? (lb2 + under) : d;
        r[k] = tr + d;
    }

    // ---- scan #2: exclusive cumsum of walk -> cs[CSI(0..LL)] ----
    run = 0.0f;
#pragma unroll
    for (int k = 0; k < 16; k++) { run += r[k]; r[k] = run; }
    ws = run;
#pragma unroll
    for (int off = 1; off < 64; off <<= 1) { float t = __shfl_up(ws, off); if (lane >= off) ws += t; }
    if (lane == 63) tmp[wid] = ws;
    __syncthreads();
    w0 = tmp[0]; w1 = tmp[1]; w2s = tmp[2]; w3 = tmp[3];
    const float grand2 = w0 + w1 + w2s + w3;
    base = (wid > 0 ? w0 : 0.0f) + (wid > 1 ? w1 : 0.0f) + (wid > 2 ? w2s : 0.0f);
    float excl2 = base + ws - run;
#pragma unroll
    for (int k = 0; k < 16; k++) {
        int t = tid * 16 + k;
        cs[CSI(t)] = excl2 + ((k == 0) ? 0.0f : r[k - 1]);
    }
    if (tid == 255) cs[CSI(LL)] = grand2;
    __syncthreads();

    // ---- box smooth (cyclic t: conflict-free cs reads; result in place) ----
    const int wh = w / 2;
    const float invw = 1.0f / (float)w;
#pragma unroll
    for (int k = 0; k < 16; k++) {
        int t  = tid + 256 * k;
        int li = t - wh;
        int hi = li + w;
        li = (li < 0) ? 0 : li;
        hi = (hi > LL) ? LL : hi;
        r[k] = (cs[CSI(hi)] - cs[CSI(li)]) * invw;
    }
    if (tid == 0)   shv[0] = r[0];      // b[0]   (t = 0)
    if (tid == 255) shv[1] = r[15];     // b[L-1] (t = 4095)
    __syncthreads();
    const float b0 = shv[0], bL = shv[1];

    // ---- detrend #2 + absmax-normalize ----
    float am = 0.0f;
#pragma unroll
    for (int k = 0; k < 16; k++) {
        int t = tid + 256 * k;
        r[k] -= b0 + (bL - b0) * ((float)t * inv_nm1);
        am = fmaxf(am, fabsf(r[k]));
    }
#pragma unroll
    for (int off = 32; off > 0; off >>= 1) am = fmaxf(am, __shfl_xor(am, off));
    if (lane == 0) tmp[wid] = am;
    __syncthreads();
    float denom = fmaxf(fmaxf(tmp[0], tmp[1]), fmaxf(tmp[2], tmp[3]));
    denom = (denom == 0.0f) ? 1.0f : denom;
    const float fac = g_omit[n] * g_scale[n] / denom;

    // ---- stash bb row at bf[t] (overwrites cs; all cs reads completed) ----
#pragma unroll
    for (int k = 0; k < 16; k++) {
        int t = tid + 256 * k;
        bf[t] = r[k] * fac;
    }
    __syncthreads();

    // ---- interp bb onto ppm axis, DIRECTLY into the pass-A register tile ----
    // X[a+4b] = (x[2p], x[2p+1]), p = tid + 256a + 1024b.  Real output planes
    // are written here too (Re(analytic) == x exactly).
    const float xlo = g_ppmr[0];
    const float xhi = g_ppmr[1];
    const float posmul = (float)(LL - 1) / (xhi - xlo);
    const size_t base1 = (size_t)NB * 2 * PP + (size_t)n * 2 * PP;  // raw
    const size_t base0 = (size_t)n * 2 * PP;                        // flipped

    auto interp1 = [&](float x) -> float {
        if (x < xlo || x > xhi) return 0.0f;
        float pos = (x - xlo) * posmul;
        int idx = (int)floorf(pos);
        idx = (idx < 0) ? 0 : ((idx > LL - 2) ? (LL - 2) : idx);
        float fr = pos - (float)idx;
        float s0 = bf[idx], s1 = bf[idx + 1];
        return s0 + (s1 - s0) * fr;
    };

    float2 X[16];
#pragma unroll
    for (int b = 0; b < 4; b++)
#pragma unroll
    for (int a = 0; a < 4; a++) {
        int p = tid + 256 * a + 1024 * b;
        float2 pm = *(const float2*)(g_ppm + 2 * p);
        float re0 = interp1(pm.x);
        float re1 = interp1(pm.y);
        X[a + 4 * b] = make_float2(re0, re1);
        *(float2*)(g_out + base1 + 2 * p)          = make_float2(re0, re1);
        *(float2*)(g_out + base0 + PP - 2 - 2 * p) = make_float2(re1, re0);
    }
    __syncthreads();   // all bb reads complete (buf stores below overwrite bf)

    // ===== forward FFT: 3 fused radix-16 passes, PH addressing =====
    // pass A: stages H=1024 then H=256 (X already loaded)
    const int baseA = tid + (tid >> 4);                   // PH(tid)
    {
        float sn, cn;
        __sincosf((-PIF / 2048.0f) * (float)tid, &sn, &cn);
        float2 Eb = make_float2(cn, sn);                  // angle -(pi/2048)(tid+256a) = base - (pi/8)a
#pragma unroll
        for (int a = 0; a < 4; a++) {
            float2 E = (a == 0) ? Eb : cmul(Eb, CFc(a));
            bf4f<4>(&X[a], E);
        }
        __sincosf((-PIF / 512.0f) * (float)tid, &sn, &cn);
        float2 E = make_float2(cn, sn);
#pragma unroll
        for (int b = 0; b < 4; b++) bf4f<1>(&X[4 * b], E);
#pragma unroll
        for (int b = 0; b < 4; b++)
#pragma unroll
        for (int a = 0; a < 4; a++)
            buf[baseA + 272 * a + 1088 * b] = X[a + 4 * b];   // PH(tid+256a+1024b)
    }
    __syncthreads();

    // pass B: stages H=64 then H=16
    const int lw = tid & 15;
    const int baseB = 272 * (tid >> 4) + lw;              // PH(256u + lw)
    {
#pragma unroll
        for (int b = 0; b < 4; b++)
#pragma unroll
        for (int a = 0; a < 4; a++)
            X[a + 4 * b] = buf[baseB + 17 * a + 68 * b];  // PH(pb + 16a + 64b)
        float sn, cn;
        __sincosf((-PIF / 128.0f) * (float)lw, &sn, &cn);
        float2 Eb = make_float2(cn, sn);                  // angle -(pi/128)(16a+lw)
#pragma unroll
        for (int a = 0; a < 4; a++) {
            float2 E = (a == 0) ? Eb : cmul(Eb, CFc(a));
            bf4f<4>(&X[a], E);
        }
        __sincosf((-PIF / 32.0f) * (float)lw, &sn, &cn);
        float2 E = make_float2(cn, sn);
#pragma unroll
        for (int b = 0; b < 4; b++) bf4f<1>(&X[4 * b], E);
#pragma unroll
        for (int b = 0; b < 4; b++)
#pragma unroll
        for (int a = 0; a < 4; a++)
            buf[baseB + 17 * a + 68 * b] = X[a + 4 * b];
    }
    __syncthreads();

    // pass C: stages H=4 then H=1 (twiddles are pure constants)
    const int baseC = 17 * tid;                           // PH(16*tid)
    {
#pragma unroll
        for (int c = 0; c < 16; c++) X[c] = buf[baseC + c];
        bf4f_nt<4>(&X[0]);
#pragma unroll
        for (int a = 1; a < 4; a++) bf4f<4>(&X[a], CFc(a));
#pragma unroll
        for (int b = 0; b < 4; b++) bf4f_nt<1>(&X[4 * b]);
#pragma unroll
        for (int c = 0; c < 16; c++) buf[baseC + c] = X[c];
    }
    __syncthreads();

    // ===== Hilbert pair-fix (unpack + filter + repack + 1/(2N)) =====
    hilbert_mid(buf, tid);
    __syncthreads();

    // ===== inverse FFT: 3 fused passes =====
    // pass C': stages H=1 then H=4
    {
#pragma unroll
        for (int c = 0; c < 16; c++) X[c] = buf[baseC + c];
#pragma unroll
        for (int b = 0; b < 4; b++) bf4i_nt<1>(&X[4 * b]);
        bf4i_nt<4>(&X[0]);
#pragma unroll
        for (int a = 1; a < 4; a++) bf4i<4>(&X[a], CIc(a));
#pragma unroll
        for (int c = 0; c < 16; c++) buf[baseC + c] = X[c];
    }
    __syncthreads();

    // pass B': stages H=16 then H=64
    {
#pragma unroll
        for (int b = 0; b < 4; b++)
#pragma unroll
        for (int a = 0; a < 4; a++)
            X[a + 4 * b] = buf[baseB + 17 * a + 68 * b];
        float sn, cn;
        __sincosf((PIF / 32.0f) * (float)lw, &sn, &cn);
        float2 E = make_float2(cn, sn);
#pragma unroll
        for (int b = 0; b < 4; b++) bf4i<1>(&X[4 * b], E);
        __sincosf((PIF / 128.0f) * (float)lw, &sn, &cn);
        float2 Eb = make_float2(cn, sn);
#pragma unroll
        for (int a = 0; a < 4; a++) {
            float2 Ea = (a == 0) ? Eb : cmul(Eb, CIc(a));
            bf4i<4>(&X[a], Ea);
        }
#pragma unroll
        for (int b = 0; b < 4; b++)
#pragma unroll
        for (int a = 0; a < 4; a++)
            buf[baseB + 17 * a + 68 * b] = X[a + 4 * b];
    }
    __syncthreads();

    // pass A': stages H=256 then H=1024; final values go straight to global
    {
#pragma unroll
        for (int b = 0; b < 4; b++)
#pragma unroll
        for (int a = 0; a < 4; a++)
            X[a + 4 * b] = buf[baseA + 272 * a + 1088 * b];
        float sn, cn;
        __sincosf((PIF / 512.0f) * (float)tid, &sn, &cn);
        float2 E = make_float2(cn, sn);
#pragma unroll
        for (int b = 0; b < 4; b++) bf4i<1>(&X[4 * b], E);
        __sincosf((PIF / 2048.0f) * (float)tid, &sn, &cn);
        float2 Eb = make_float2(cn, sn);
#pragma unroll
        for (int a = 0; a < 4; a++) {
            float2 Ea = (a == 0) ? Eb : cmul(Eb, CIc(a));
            bf4i<4>(&X[a], Ea);
        }
        // X[a+4b] = (Hx[2p], Hx[2p+1]), p = tid + 256a + 1024b
#pragma unroll
        for (int b = 0; b < 4; b++)
#pragma unroll
        for (int a = 0; a < 4; a++) {
            int p = tid + 256 * a + 1024 * b;
            float2 vv = X[a + 4 * b];
            *(float2*)(g_out + base1 + PP + 2 * p)         = vv;                        // raw imag
            *(float2*)(g_out + base0 + 2 * PP - 2 - 2 * p) = make_float2(vv.y, vv.x);   // flipped imag
        }
    }
}

extern "C" void kernel_launch(void* const* d_in, const int* in_sizes, int n_in,
                              void* d_out, int out_size, void* d_ws, size_t ws_size,
                              hipStream_t stream)
{
    const float* start = (const float*)d_in[0];
    const float* end_  = (const float*)d_in[1];
    const float* stdv  = (const float*)d_in[2];
    const float* lowb  = (const float*)d_in[3];
    const float* upb   = (const float*)d_in[4];
    const int*   win   = (const int*)d_in[5];
    const float* scl   = (const float*)d_in[6];
    const float* noise = (const float*)d_in[7];
    const float* omit  = (const float*)d_in[8];
    const float* ppm   = (const float*)d_in[9];
    const float* ppmr  = (const float*)d_in[10];
    float* out = (float*)d_out;

    hipLaunchKernelGGL(k_all, dim3(NB), dim3(256), 0, stream,
                       start, end_, stdv, lowb, upb, win, scl, noise, omit,
                       ppm, ppmr, out);
}

// Round 5
// 176.003 us; speedup vs baseline: 1.0711x; 1.0447x over previous
//
#include <hip/hip_runtime.h>

#define NB 1024
#define LL 4096
#define PP 8192
#define FN 4096            // complex FFT length = PP/2 (real-packed Hilbert)

#define PIF 3.14159265358979323846f

__device__ __forceinline__ float2 cadd(float2 a, float2 b){ return make_float2(a.x+b.x, a.y+b.y); }
__device__ __forceinline__ float2 csub(float2 a, float2 b){ return make_float2(a.x-b.x, a.y-b.y); }
__device__ __forceinline__ float2 cmul(float2 a, float2 b){ return make_float2(a.x*b.x - a.y*b.y, a.x*b.y + a.y*b.x); }

// additive LDS pad on the float2 index: bijective, compile-time ds offsets per pass
__device__ __forceinline__ int PH2(int p){ return p + 2*(p >> 4); }

// base-8 digit reversal of a 12-bit index (4 digits) — radix-8 DIF output permutation
__device__ __forceinline__ int rev8(int k){
    return ((k & 7) << 9) | (((k >> 3) & 7) << 6) | (((k >> 6) & 7) << 3) | ((k >> 9) & 7);
}

// ---- radix-8 DFT core, forward (in place, time order in -> freq order r out) ----
__device__ __forceinline__ void core8f(float2* x){
    const float c8 = 0.70710678118654752f;
    float2 e0=cadd(x[0],x[4]), e1=cadd(x[1],x[5]), e2=cadd(x[2],x[6]), e3=cadd(x[3],x[7]);
    float2 o0=csub(x[0],x[4]), o1=csub(x[1],x[5]), o2=csub(x[2],x[6]), o3=csub(x[3],x[7]);
    float2 t1 = make_float2(c8*(o1.x + o1.y), c8*(o1.y - o1.x));   // o1*w8^1, w8=(c,-c)
    float2 t2 = make_float2(o2.y, -o2.x);                          // o2*(-i)
    float2 t3 = make_float2(c8*(o3.y - o3.x), -c8*(o3.x + o3.y));  // o3*w8^3=(-c,-c)
    float2 a0=cadd(e0,e2), a1=cadd(e1,e3), a2=csub(e0,e2), a3=csub(e1,e3);
    x[0]=cadd(a0,a1); x[4]=csub(a0,a1);
    x[2]=make_float2(a2.x + a3.y, a2.y - a3.x);                    // a2 - i a3
    x[6]=make_float2(a2.x - a3.y, a2.y + a3.x);
    float2 b0=cadd(o0,t2), b1=cadd(t1,t3), b2=csub(o0,t2), b3=csub(t1,t3);
    x[1]=cadd(b0,b1); x[5]=csub(b0,b1);
    x[3]=make_float2(b2.x + b3.y, b2.y - b3.x);
    x[7]=make_float2(b2.x - b3.y, b2.y + b3.x);
}
// ---- radix-8 core, inverse/conjugate (unnormalized IDFT) ----
__device__ __forceinline__ void core8i(float2* x){
    const float c8 = 0.70710678118654752f;
    float2 e0=cadd(x[0],x[4]), e1=cadd(x[1],x[5]), e2=cadd(x[2],x[6]), e3=cadd(x[3],x[7]);
    float2 o0=csub(x[0],x[4]), o1=csub(x[1],x[5]), o2=csub(x[2],x[6]), o3=csub(x[3],x[7]);
    float2 t1 = make_float2(c8*(o1.x - o1.y), c8*(o1.y + o1.x));   // o1*(c, c)
    float2 t2 = make_float2(-o2.y, o2.x);                          // o2*(+i)
    float2 t3 = make_float2(-c8*(o3.x + o3.y), c8*(o3.x - o3.y));  // o3*(-c, c)
    float2 a0=cadd(e0,e2), a1=cadd(e1,e3), a2=csub(e0,e2), a3=csub(e1,e3);
    x[0]=cadd(a0,a1); x[4]=csub(a0,a1);
    x[2]=make_float2(a2.x - a3.y, a2.y + a3.x);                    // a2 + i a3
    x[6]=make_float2(a2.x + a3.y, a2.y - a3.x);
    float2 b0=cadd(o0,t2), b1=cadd(t1,t3), b2=csub(o0,t2), b3=csub(t1,t3);
    x[1]=cadd(b0,b1); x[5]=csub(b0,b1);
    x[3]=make_float2(b2.x - b3.y, b2.y + b3.x);
    x[7]=make_float2(b2.x + b3.y, b2.y - b3.x);
}

__global__ __launch_bounds__(512, 6) void k_all(
    const float* __restrict__ g_start,
    const float* __restrict__ g_end,
    const float* __restrict__ g_std,
    const float* __restrict__ g_low,
    const float* __restrict__ g_up,
    const int*   __restrict__ g_win,
    const float* __restrict__ g_scale,
    const float* __restrict__ g_noise,
    const float* __restrict__ g_omit,
    const float* __restrict__ g_ppm,
    const float* __restrict__ g_ppmr,
    float* __restrict__ g_out)
{
    __shared__ alignas(16) float2 buf[4608];   // 36 KB -> 3 blocks/CU (24 waves/CU)
    float* bf  = (float*)buf;                  // 9216 floats
#define CSI(t) ((t) + ((t) >> 5))
    float* cs  = bf;                           // CSI(0..4096) -> 0..4224
    float* tmp = bf + 4226;                    // 16 floats (8 wave partials x2)
    float* shv = bf + 4242;                    // 2 floats

    const int n    = blockIdx.x;
    const int tid  = threadIdx.x;
    const int lane = tid & 63;
    const int wid  = tid >> 6;                 // 8 waves / block
    const float st = g_start[n];
    const float en = g_end[n];
    const float sd = g_std[n];
    const float lo = g_low[n];
    const float up = g_up[n];
    const int   w  = g_win[n];
    const float inv_nm1 = 1.0f / (float)(LL - 1);

    // ---- load 8 fp32 noise steps/thread ----
    float r[8];
    {
        const float4* p = (const float4*)(g_noise + (size_t)n * LL) + (size_t)tid * 2;
        float4 ta = p[0], tb = p[1];
        r[0]=ta.x; r[1]=ta.y; r[2]=ta.z; r[3]=ta.w;
        r[4]=tb.x; r[5]=tb.y; r[6]=tb.z; r[7]=tb.w;
    }
#pragma unroll
    for (int k = 0; k < 8; k++) r[k] = sd * (r[k] - 0.5f);

    // ---- scan #1 (rand = inclusive cumsum) ----
    float run = 0.0f;
#pragma unroll
    for (int k = 0; k < 8; k++) { run += r[k]; r[k] = run; }
    float ws = run;
#pragma unroll
    for (int off = 1; off < 64; off <<= 1) { float t = __shfl_up(ws, off); if (lane >= off) ws += t; }
    if (lane == 63) tmp[wid] = ws;
    if (tid == 0)   shv[0] = r[0];             // rand[0]
    __syncthreads();                           // B1
    float t0=tmp[0],t1=tmp[1],t2=tmp[2],t3=tmp[3],t4=tmp[4],t5=tmp[5],t6=tmp[6],t7=tmp[7];
    const float rT = ((t0+t1)+(t2+t3))+((t4+t5)+(t6+t7));
    const float r0 = shv[0];
    float base = (wid>0?t0:0.f)+(wid>1?t1:0.f)+(wid>2?t2:0.f)+(wid>3?t3:0.f)
               + (wid>4?t4:0.f)+(wid>5?t5:0.f)+(wid>6?t6:0.f);
    float excl = base + ws - run;
    __syncthreads();                           // B2 (protect tmp)

    // ---- detrend walk (in place), min/max ----
    float mx = -INFINITY, mn = INFINITY;
#pragma unroll
    for (int k = 0; k < 8; k++) {
        int t = tid * 8 + k;
        float d = (excl + r[k]) - (r0 + (rT - r0) * ((float)t * inv_nm1));
        r[k] = d;
        mx = fmaxf(mx, d); mn = fminf(mn, d);
    }
#pragma unroll
    for (int off = 32; off > 0; off >>= 1) {
        mx = fmaxf(mx, __shfl_xor(mx, off));
        mn = fminf(mn, __shfl_xor(mn, off));
    }
    if (lane == 0) { tmp[wid] = mx; tmp[8 + wid] = mn; }
    __syncthreads();                           // B3
    mx = fmaxf(fmaxf(fmaxf(tmp[0],tmp[1]),fmaxf(tmp[2],tmp[3])),
               fmaxf(fmaxf(tmp[4],tmp[5]),fmaxf(tmp[6],tmp[7])));
    mn = fminf(fminf(fminf(tmp[8],tmp[9]),fminf(tmp[10],tmp[11])),
               fminf(fminf(tmp[12],tmp[13]),fminf(tmp[14],tmp[15])));
    __syncthreads();                           // B4 (protect tmp)

    const float qs = fmaxf(1.0f, (mx - mn) / (up - lo));

    // ---- squeeze + reflect + trend -> walk values (in place) ----
#pragma unroll
    for (int k = 0; k < 8; k++) {
        int t = tid * 8 + k;
        float tr  = st + (en - st) * ((float)t * inv_nm1);
        float ub  = up - tr;
        float lb2 = lo - tr;
        float d = r[k] / qs;
        float over = d - ub;
        d = (over >= 0.0f) ? (ub - over) : d;
        float under = lb2 - d;
        d = (under >= 0.0f) ? (lb2 + under) : d;
        r[k] = tr + d;
    }

    // ---- scan #2: exclusive cumsum of walk -> cs[CSI(0..LL)] ----
    run = 0.0f;
#pragma unroll
    for (int k = 0; k < 8; k++) { run += r[k]; r[k] = run; }
    ws = run;
#pragma unroll
    for (int off = 1; off < 64; off <<= 1) { float t = __shfl_up(ws, off); if (lane >= off) ws += t; }
    if (lane == 63) tmp[wid] = ws;
    __syncthreads();                           // B5
    t0=tmp[0];t1=tmp[1];t2=tmp[2];t3=tmp[3];t4=tmp[4];t5=tmp[5];t6=tmp[6];t7=tmp[7];
    const float grand2 = ((t0+t1)+(t2+t3))+((t4+t5)+(t6+t7));
    base = (wid>0?t0:0.f)+(wid>1?t1:0.f)+(wid>2?t2:0.f)+(wid>3?t3:0.f)
         + (wid>4?t4:0.f)+(wid>5?t5:0.f)+(wid>6?t6:0.f);
    float excl2 = base + ws - run;
#pragma unroll
    for (int k = 0; k < 8; k++) {
        int t = tid * 8 + k;
        cs[CSI(t)] = excl2 + ((k == 0) ? 0.0f : r[k - 1]);
    }
    if (tid == 511) cs[CSI(LL)] = grand2;
    __syncthreads();                           // B6

    // ---- box smooth (cyclic t: conflict-free cs reads; result in place) ----
    const int wh = w / 2;
    const float invw = 1.0f / (float)w;
#pragma unroll
    for (int k = 0; k < 8; k++) {
        int t  = tid + 512 * k;
        int li = t - wh;
        int hi = li + w;
        li = (li < 0) ? 0 : li;
        hi = (hi > LL) ? LL : hi;
        r[k] = (cs[CSI(hi)] - cs[CSI(li)]) * invw;
    }
    if (tid == 0)   shv[0] = r[0];      // b[0]   (t = 0)
    if (tid == 511) shv[1] = r[7];      // b[L-1] (t = 4095)
    __syncthreads();                           // B7
    const float b0 = shv[0], bL = shv[1];

    // ---- detrend #2 + absmax-normalize ----
    float am = 0.0f;
#pragma unroll
    for (int k = 0; k < 8; k++) {
        int t = tid + 512 * k;
        r[k] -= b0 + (bL - b0) * ((float)t * inv_nm1);
        am = fmaxf(am, fabsf(r[k]));
    }
#pragma unroll
    for (int off = 32; off > 0; off >>= 1) am = fmaxf(am, __shfl_xor(am, off));
    if (lane == 0) tmp[wid] = am;
    __syncthreads();                           // B8
    float denom = fmaxf(fmaxf(fmaxf(tmp[0],tmp[1]),fmaxf(tmp[2],tmp[3])),
                        fmaxf(fmaxf(tmp[4],tmp[5]),fmaxf(tmp[6],tmp[7])));
    denom = (denom == 0.0f) ? 1.0f : denom;
    const float fac = g_omit[n] * g_scale[n] / denom;
    __syncthreads();                           // B9 (all tmp reads done)

    // ---- stash bb row at bf[t] (overwrites cs; cs reads completed at B7) ----
#pragma unroll
    for (int k = 0; k < 8; k++) {
        int t = tid + 512 * k;
        bf[t] = r[k] * fac;
    }
    __syncthreads();                           // B10

    // ---- interp bb onto ppm axis -> X[8] registers (= pass-1 butterfly inputs) ----
    const float xlo = g_ppmr[0];
    const float xhi = g_ppmr[1];
    const float posmul = (float)(LL - 1) / (xhi - xlo);
    const size_t base1 = (size_t)NB * 2 * PP + (size_t)n * 2 * PP;  // raw
    const size_t base0 = (size_t)n * 2 * PP;                        // flipped

    auto interp1 = [&](float x) -> float {
        if (x < xlo || x > xhi) return 0.0f;
        float pos = (x - xlo) * posmul;
        int idx = (int)floorf(pos);
        idx = (idx < 0) ? 0 : ((idx > LL - 2) ? (LL - 2) : idx);
        float fr = pos - (float)idx;
        float s0 = bf[idx], s1 = bf[idx + 1];
        return s0 + (s1 - s0) * fr;
    };

    float2 X[8];
#pragma unroll
    for (int m = 0; m < 8; m++) {
        int p = tid + 512 * m;
        float2 pm = *(const float2*)(g_ppm + 2 * p);
        float re0 = interp1(pm.x);
        float re1 = interp1(pm.y);
        X[m] = make_float2(re0, re1);
        *(float2*)(g_out + base1 + 2 * p)          = make_float2(re0, re1);   // raw real
        *(float2*)(g_out + base0 + PP - 2 - 2 * p) = make_float2(re1, re0);   // flipped real
    }
    __syncthreads();                           // B11 (all bb reads complete)

    // ===== forward FFT: 4 radix-8 DIF passes (H = 512, 64, 8, 1) =====
    const int bA = tid + 2 * (tid >> 4);                 // PH2(tid); offsets 576*r
    {
        // pass 1 (H=512): inputs already in X (p = tid + 512d)
        core8f(X);
        float sn, cn; __sincosf((-PIF / 2048.0f) * (float)tid, &sn, &cn);
        float2 E = make_float2(cn, sn), Er = E;
        buf[bA]        = X[0];
        buf[bA +  576] = cmul(X[1], Er); Er = cmul(Er, E);
        buf[bA + 1152] = cmul(X[2], Er); Er = cmul(Er, E);
        buf[bA + 1728] = cmul(X[3], Er); Er = cmul(Er, E);
        buf[bA + 2304] = cmul(X[4], Er); Er = cmul(Er, E);
        buf[bA + 2880] = cmul(X[5], Er); Er = cmul(Er, E);
        buf[bA + 3456] = cmul(X[6], Er); Er = cmul(Er, E);
        buf[bA + 4032] = cmul(X[7], Er);
    }
    __syncthreads();                           // B12

    const int j2 = tid & 63;
    const int bB = (tid >> 6) * 576 + j2 + 2 * (j2 >> 4);   // offsets 72*r
    {
        // pass 2 (H=64)
#pragma unroll
        for (int d = 0; d < 8; d++) X[d] = buf[bB + 72 * d];
        core8f(X);
        float sn, cn; __sincosf((-PIF / 256.0f) * (float)j2, &sn, &cn);
        float2 E = make_float2(cn, sn), Er = E;
        buf[bB]       = X[0];
        buf[bB +  72] = cmul(X[1], Er); Er = cmul(Er, E);
        buf[bB + 144] = cmul(X[2], Er); Er = cmul(Er, E);
        buf[bB + 216] = cmul(X[3], Er); Er = cmul(Er, E);
        buf[bB + 288] = cmul(X[4], Er); Er = cmul(Er, E);
        buf[bB + 360] = cmul(X[5], Er); Er = cmul(Er, E);
        buf[bB + 432] = cmul(X[6], Er); Er = cmul(Er, E);
        buf[bB + 504] = cmul(X[7], Er);
    }
    __syncthreads();                           // B13

    const int j3 = tid & 7;
    const int bC = (tid >> 3) * 72 + j3;       // offsets 8d + 2*(d>>1): 0,8,18,26,36,44,54,62
    {
        // pass 3 (H=8)
        X[0]=buf[bC];    X[1]=buf[bC+8];  X[2]=buf[bC+18]; X[3]=buf[bC+26];
        X[4]=buf[bC+36]; X[5]=buf[bC+44]; X[6]=buf[bC+54]; X[7]=buf[bC+62];
        core8f(X);
        float sn, cn; __sincosf((-PIF / 32.0f) * (float)j3, &sn, &cn);
        float2 E = make_float2(cn, sn), Er = E;
        buf[bC]    = X[0];
        buf[bC+ 8] = cmul(X[1], Er); Er = cmul(Er, E);
        buf[bC+18] = cmul(X[2], Er); Er = cmul(Er, E);
        buf[bC+26] = cmul(X[3], Er); Er = cmul(Er, E);
        buf[bC+36] = cmul(X[4], Er); Er = cmul(Er, E);
        buf[bC+44] = cmul(X[5], Er); Er = cmul(Er, E);
        buf[bC+54] = cmul(X[6], Er); Er = cmul(Er, E);
        buf[bC+62] = cmul(X[7], Er);
    }
    __syncthreads();                           // B14

    const int f4 = 4 * tid + (tid >> 1);       // float4 index of PH2(8*tid)/2
    float4* b4 = reinterpret_cast<float4*>(buf);
    {
        // pass 4 (H=1, twiddle-free), contiguous b128
        float4 a0 = b4[f4], a1 = b4[f4+1], a2 = b4[f4+2], a3 = b4[f4+3];
        X[0]=make_float2(a0.x,a0.y); X[1]=make_float2(a0.z,a0.w);
        X[2]=make_float2(a1.x,a1.y); X[3]=make_float2(a1.z,a1.w);
        X[4]=make_float2(a2.x,a2.y); X[5]=make_float2(a2.z,a2.w);
        X[6]=make_float2(a3.x,a3.y); X[7]=make_float2(a3.z,a3.w);
        core8f(X);
        b4[f4]   = make_float4(X[0].x,X[0].y,X[1].x,X[1].y);
        b4[f4+1] = make_float4(X[2].x,X[2].y,X[3].x,X[3].y);
        b4[f4+2] = make_float4(X[4].x,X[4].y,X[5].x,X[5].y);
        b4[f4+3] = make_float4(X[6].x,X[6].y,X[7].x,X[7].y);
    }
    __syncthreads();                           // B15

    // ===== Hilbert pair-fix: buf[PH2(rev8(k))] = Z[k] -> Z'[k], 4 pairs/thread =====
    {
        const float s = 1.0f / (2.0f * (float)FN);
#pragma unroll
        for (int m = 0; m < 4; m++) {
            int k = ((tid & 31) << 6) | ((tid >> 5) << 2) | m;   // k in [0,2047]
            if (k == 0) {
                buf[0] = make_float2(0.0f, 0.0f);                // k=0 (rev8(0)=0)
                float2 Z = buf[4];                               // k=2048: rev8=4, self-pair
                buf[4] = make_float2(-2.0f*s*Z.y, 2.0f*s*Z.x);
            } else {
                int pk = PH2(rev8(k));
                int pj = PH2(rev8(FN - k));
                float2 Zk = buf[pk];
                float2 Zj = buf[pj];
                float ux = Zk.x + Zj.x, uy = Zk.y - Zj.y;        // u = Zk + conj(Zj)
                float vx = Zk.x - Zj.x, vy = Zk.y + Zj.y;        // v = Zk - conj(Zj)
                float sn, cn; __sincosf((PIF/(float)FN) * (float)k, &sn, &cn);  // conj(W)
                float2 zk, zj;
                zk.x = s * ((ux*cn - uy*sn) - (vx*cn + vy*sn));
                zk.y = s * ((ux*sn + uy*cn) + (vx*sn - vy*cn));
                float u2x = ux,  u2y = -uy;
                float v2x = -vx, v2y = vy;
                zj.x = s * ((v2x*cn - v2y*sn) - (u2x*cn + u2y*sn));
                zj.y = s * ((v2x*sn + v2y*cn) + (u2x*sn - u2y*cn));
                buf[pk] = zk;
                buf[pj] = zj;
            }
        }
    }
    __syncthreads();                           // B16

    // ===== inverse FFT: 4 radix-8 DIT passes (H = 1, 8, 64, 512) =====
    {
        // pass 1' (H=1, twiddle-free)
        float4 a0 = b4[f4], a1 = b4[f4+1], a2 = b4[f4+2], a3 = b4[f4+3];
        X[0]=make_float2(a0.x,a0.y); X[1]=make_float2(a0.z,a0.w);
        X[2]=make_float2(a1.x,a1.y); X[3]=make_float2(a1.z,a1.w);
        X[4]=make_float2(a2.x,a2.y); X[5]=make_float2(a2.z,a2.w);
        X[6]=make_float2(a3.x,a3.y); X[7]=make_float2(a3.z,a3.w);
        core8i(X);
        b4[f4]   = make_float4(X[0].x,X[0].y,X[1].x,X[1].y);
        b4[f4+1] = make_float4(X[2].x,X[2].y,X[3].x,X[3].y);
        b4[f4+2] = make_float4(X[4].x,X[4].y,X[5].x,X[5].y);
        b4[f4+3] = make_float4(X[6].x,X[6].y,X[7].x,X[7].y);
    }
    __syncthreads();                           // B17

    {
        // pass 2' (H=8): conj twiddle on inputs, then inverse core
        X[0]=buf[bC];    X[1]=buf[bC+8];  X[2]=buf[bC+18]; X[3]=buf[bC+26];
        X[4]=buf[bC+36]; X[5]=buf[bC+44]; X[6]=buf[bC+54]; X[7]=buf[bC+62];
        float sn, cn; __sincosf((PIF / 32.0f) * (float)j3, &sn, &cn);
        float2 E = make_float2(cn, sn), Er = E;
        X[1]=cmul(X[1],Er); Er=cmul(Er,E);
        X[2]=cmul(X[2],Er); Er=cmul(Er,E);
        X[3]=cmul(X[3],Er); Er=cmul(Er,E);
        X[4]=cmul(X[4],Er); Er=cmul(Er,E);
        X[5]=cmul(X[5],Er); Er=cmul(Er,E);
        X[6]=cmul(X[6],Er); Er=cmul(Er,E);
        X[7]=cmul(X[7],Er);
        core8i(X);
        buf[bC]=X[0];    buf[bC+8]=X[1];  buf[bC+18]=X[2]; buf[bC+26]=X[3];
        buf[bC+36]=X[4]; buf[bC+44]=X[5]; buf[bC+54]=X[6]; buf[bC+62]=X[7];
    }
    __syncthreads();                           // B18

    {
        // pass 3' (H=64)
#pragma unroll
        for (int d = 0; d < 8; d++) X[d] = buf[bB + 72 * d];
        float sn, cn; __sincosf((PIF / 256.0f) * (float)j2, &sn, &cn);
        float2 E = make_float2(cn, sn), Er = E;
        X[1]=cmul(X[1],Er); Er=cmul(Er,E);
        X[2]=cmul(X[2],Er); Er=cmul(Er,E);
        X[3]=cmul(X[3],Er); Er=cmul(Er,E);
        X[4]=cmul(X[4],Er); Er=cmul(Er,E);
        X[5]=cmul(X[5],Er); Er=cmul(Er,E);
        X[6]=cmul(X[6],Er); Er=cmul(Er,E);
        X[7]=cmul(X[7],Er);
        core8i(X);
#pragma unroll
        for (int d = 0; d < 8; d++) buf[bB + 72 * d] = X[d];
    }
    __syncthreads();                           // B19

    {
        // pass 4' (H=512): final; outputs go straight to global imag planes
#pragma unroll
        for (int d = 0; d < 8; d++) X[d] = buf[bA + 576 * d];
        float sn, cn; __sincosf((PIF / 2048.0f) * (float)tid, &sn, &cn);
        float2 E = make_float2(cn, sn), Er = E;
        X[1]=cmul(X[1],Er); Er=cmul(Er,E);
        X[2]=cmul(X[2],Er); Er=cmul(Er,E);
        X[3]=cmul(X[3],Er); Er=cmul(Er,E);
        X[4]=cmul(X[4],Er); Er=cmul(Er,E);
        X[5]=cmul(X[5],Er); Er=cmul(Er,E);
        X[6]=cmul(X[6],Er); Er=cmul(Er,E);
        X[7]=cmul(X[7],Er);
        core8i(X);
        // X[d] = (Hx[2p], Hx[2p+1]), p = tid + 512d
#pragma unroll
        for (int d = 0; d < 8; d++) {
            int p = tid + 512 * d;
            float2 vv = X[d];
            *(float2*)(g_out + base1 + PP + 2 * p)         = vv;                        // raw imag
            *(float2*)(g_out + base0 + 2 * PP - 2 - 2 * p) = make_float2(vv.y, vv.x);   // flipped imag
        }
    }
}

extern "C" void kernel_launch(void* const* d_in, const int* in_sizes, int n_in,
                              void* d_out, int out_size, void* d_ws, size_t ws_size,
                              hipStream_t stream)
{
    const float* start = (const float*)d_in[0];
    const float* end_  = (const float*)d_in[1];
    const float* stdv  = (const float*)d_in[2];
    const float* lowb  = (const float*)d_in[3];
    const float* upb   = (const float*)d_in[4];
    const int*   win   = (const int*)d_in[5];
    const float* scl   = (const float*)d_in[6];
    const float* noise = (const float*)d_in[7];
    const float* omit  = (const float*)d_in[8];
    const float* ppm   = (const float*)d_in[9];
    const float* ppmr  = (const float*)d_in[10];
    float* out = (float*)d_out;

    hipLaunchKernelGGL(k_all, dim3(NB), dim3(512), 0, stream,
                       start, end_, stdv, lowb, upb, win, scl, noise, omit,
                       ppm, ppmr, out);
}

// Round 6
// 175.848 us; speedup vs baseline: 1.0721x; 1.0009x over previous
//
#include <hip/hip_runtime.h>

#define NB 1024
#define LL 4096
#define PP 8192
#define FN 4096            // complex FFT length = PP/2 (real-packed Hilbert)

#define PIF 3.14159265358979323846f

__device__ __forceinline__ float2 cadd(float2 a, float2 b){ return make_float2(a.x+b.x, a.y+b.y); }
__device__ __forceinline__ float2 csub(float2 a, float2 b){ return make_float2(a.x-b.x, a.y-b.y); }
__device__ __forceinline__ float2 cmul(float2 a, float2 b){ return make_float2(a.x*b.x - a.y*b.y, a.x*b.y + a.y*b.x); }

// additive LDS pad on the float2 index: bijective, compile-time ds offsets per pass
__device__ __forceinline__ int PH2(int p){ return p + 2*(p >> 4); }

// base-8 digit reversal of a 12-bit index (4 digits) — radix-8 DIF output permutation
__device__ __forceinline__ int rev8(int k){
    return ((k & 7) << 9) | (((k >> 3) & 7) << 6) | (((k >> 6) & 7) << 3) | ((k >> 9) & 7);
}

// ---- radix-8 DFT core, forward (in place, time order in -> freq order r out) ----
__device__ __forceinline__ void core8f(float2* x){
    const float c8 = 0.70710678118654752f;
    float2 e0=cadd(x[0],x[4]), e1=cadd(x[1],x[5]), e2=cadd(x[2],x[6]), e3=cadd(x[3],x[7]);
    float2 o0=csub(x[0],x[4]), o1=csub(x[1],x[5]), o2=csub(x[2],x[6]), o3=csub(x[3],x[7]);
    float2 t1 = make_float2(c8*(o1.x + o1.y), c8*(o1.y - o1.x));   // o1*w8^1, w8=(c,-c)
    float2 t2 = make_float2(o2.y, -o2.x);                          // o2*(-i)
    float2 t3 = make_float2(c8*(o3.y - o3.x), -c8*(o3.x + o3.y));  // o3*w8^3=(-c,-c)
    float2 a0=cadd(e0,e2), a1=cadd(e1,e3), a2=csub(e0,e2), a3=csub(e1,e3);
    x[0]=cadd(a0,a1); x[4]=csub(a0,a1);
    x[2]=make_float2(a2.x + a3.y, a2.y - a3.x);                    // a2 - i a3
    x[6]=make_float2(a2.x - a3.y, a2.y + a3.x);
    float2 b0=cadd(o0,t2), b1=cadd(t1,t3), b2=csub(o0,t2), b3=csub(t1,t3);
    x[1]=cadd(b0,b1); x[5]=csub(b0,b1);
    x[3]=make_float2(b2.x + b3.y, b2.y - b3.x);
    x[7]=make_float2(b2.x - b3.y, b2.y + b3.x);
}
// ---- radix-8 core, inverse/conjugate (unnormalized IDFT) ----
__device__ __forceinline__ void core8i(float2* x){
    const float c8 = 0.70710678118654752f;
    float2 e0=cadd(x[0],x[4]), e1=cadd(x[1],x[5]), e2=cadd(x[2],x[6]), e3=cadd(x[3],x[7]);
    float2 o0=csub(x[0],x[4]), o1=csub(x[1],x[5]), o2=csub(x[2],x[6]), o3=csub(x[3],x[7]);
    float2 t1 = make_float2(c8*(o1.x - o1.y), c8*(o1.y + o1.x));   // o1*(c, c)
    float2 t2 = make_float2(-o2.y, o2.x);                          // o2*(+i)
    float2 t3 = make_float2(-c8*(o3.x + o3.y), c8*(o3.x - o3.y));  // o3*(-c, c)
    float2 a0=cadd(e0,e2), a1=cadd(e1,e3), a2=csub(e0,e2), a3=csub(e1,e3);
    x[0]=cadd(a0,a1); x[4]=csub(a0,a1);
    x[2]=make_float2(a2.x - a3.y, a2.y + a3.x);                    // a2 + i a3
    x[6]=make_float2(a2.x + a3.y, a2.y - a3.x);
    float2 b0=cadd(o0,t2), b1=cadd(t1,t3), b2=csub(o0,t2), b3=csub(t1,t3);
    x[1]=cadd(b0,b1); x[5]=csub(b0,b1);
    x[3]=make_float2(b2.x - b3.y, b2.y + b3.x);
    x[7]=make_float2(b2.x + b3.y, b2.y - b3.x);
}

__global__ __launch_bounds__(512, 8) void k_all(
    const float* __restrict__ g_start,
    const float* __restrict__ g_end,
    const float* __restrict__ g_std,
    const float* __restrict__ g_low,
    const float* __restrict__ g_up,
    const int*   __restrict__ g_win,
    const float* __restrict__ g_scale,
    const float* __restrict__ g_noise,
    const float* __restrict__ g_omit,
    const float* __restrict__ g_ppm,
    const float* __restrict__ g_ppmr,
    float* __restrict__ g_out)
{
    __shared__ alignas(16) float2 buf[4608];   // 36 KB -> 4 blocks/CU (32 waves/CU, grid fully co-resident)
    float* bf  = (float*)buf;                  // 9216 floats
#define CSI(t) ((t) + ((t) >> 5))
    float* cs  = bf;                           // CSI(0..4096) -> 0..4224
    float* tmp = bf + 4226;                    // 16 floats (8 wave partials x2)
    float* shv = bf + 4242;                    // 2 floats

    const int n    = blockIdx.x;
    const int tid  = threadIdx.x;
    const int lane = tid & 63;
    const int wid  = tid >> 6;                 // 8 waves / block
    const float st = g_start[n];
    const float en = g_end[n];
    const float sd = g_std[n];
    const float lo = g_low[n];
    const float up = g_up[n];
    const int   w  = g_win[n];
    const float inv_nm1 = 1.0f / (float)(LL - 1);

    // ---- load 8 fp32 noise steps/thread ----
    float r[8];
    {
        const float4* p = (const float4*)(g_noise + (size_t)n * LL) + (size_t)tid * 2;
        float4 ta = p[0], tb = p[1];
        r[0]=ta.x; r[1]=ta.y; r[2]=ta.z; r[3]=ta.w;
        r[4]=tb.x; r[5]=tb.y; r[6]=tb.z; r[7]=tb.w;
    }
#pragma unroll
    for (int k = 0; k < 8; k++) r[k] = sd * (r[k] - 0.5f);

    // ---- scan #1 (rand = inclusive cumsum) ----
    float run = 0.0f;
#pragma unroll
    for (int k = 0; k < 8; k++) { run += r[k]; r[k] = run; }
    float ws = run;
#pragma unroll
    for (int off = 1; off < 64; off <<= 1) { float t = __shfl_up(ws, off); if (lane >= off) ws += t; }
    if (lane == 63) tmp[wid] = ws;
    if (tid == 0)   shv[0] = r[0];             // rand[0]
    __syncthreads();                           // B1
    float t0=tmp[0],t1=tmp[1],t2=tmp[2],t3=tmp[3],t4=tmp[4],t5=tmp[5],t6=tmp[6],t7=tmp[7];
    const float rT = ((t0+t1)+(t2+t3))+((t4+t5)+(t6+t7));
    const float r0 = shv[0];
    float base = (wid>0?t0:0.f)+(wid>1?t1:0.f)+(wid>2?t2:0.f)+(wid>3?t3:0.f)
               + (wid>4?t4:0.f)+(wid>5?t5:0.f)+(wid>6?t6:0.f);
    float excl = base + ws - run;
    __syncthreads();                           // B2 (protect tmp)

    // ---- detrend walk (in place), min/max ----
    float mx = -INFINITY, mn = INFINITY;
#pragma unroll
    for (int k = 0; k < 8; k++) {
        int t = tid * 8 + k;
        float d = (excl + r[k]) - (r0 + (rT - r0) * ((float)t * inv_nm1));
        r[k] = d;
        mx = fmaxf(mx, d); mn = fminf(mn, d);
    }
#pragma unroll
    for (int off = 32; off > 0; off >>= 1) {
        mx = fmaxf(mx, __shfl_xor(mx, off));
        mn = fminf(mn, __shfl_xor(mn, off));
    }
    if (lane == 0) { tmp[wid] = mx; tmp[8 + wid] = mn; }
    __syncthreads();                           // B3
    mx = fmaxf(fmaxf(fmaxf(tmp[0],tmp[1]),fmaxf(tmp[2],tmp[3])),
               fmaxf(fmaxf(tmp[4],tmp[5]),fmaxf(tmp[6],tmp[7])));
    mn = fminf(fminf(fminf(tmp[8],tmp[9]),fminf(tmp[10],tmp[11])),
               fminf(fminf(tmp[12],tmp[13]),fminf(tmp[14],tmp[15])));
    __syncthreads();                           // B4 (protect tmp)

    const float qs = fmaxf(1.0f, (mx - mn) / (up - lo));

    // ---- squeeze + reflect + trend -> walk values (in place) ----
#pragma unroll
    for (int k = 0; k < 8; k++) {
        int t = tid * 8 + k;
        float tr  = st + (en - st) * ((float)t * inv_nm1);
        float ub  = up - tr;
        float lb2 = lo - tr;
        float d = r[k] / qs;
        float over = d - ub;
        d = (over >= 0.0f) ? (ub - over) : d;
        float under = lb2 - d;
        d = (under >= 0.0f) ? (lb2 + under) : d;
        r[k] = tr + d;
    }

    // ---- scan #2: exclusive cumsum of walk -> cs[CSI(0..LL)] ----
    run = 0.0f;
#pragma unroll
    for (int k = 0; k < 8; k++) { run += r[k]; r[k] = run; }
    ws = run;
#pragma unroll
    for (int off = 1; off < 64; off <<= 1) { float t = __shfl_up(ws, off); if (lane >= off) ws += t; }
    if (lane == 63) tmp[wid] = ws;
    __syncthreads();                           // B5
    t0=tmp[0];t1=tmp[1];t2=tmp[2];t3=tmp[3];t4=tmp[4];t5=tmp[5];t6=tmp[6];t7=tmp[7];
    const float grand2 = ((t0+t1)+(t2+t3))+((t4+t5)+(t6+t7));
    base = (wid>0?t0:0.f)+(wid>1?t1:0.f)+(wid>2?t2:0.f)+(wid>3?t3:0.f)
         + (wid>4?t4:0.f)+(wid>5?t5:0.f)+(wid>6?t6:0.f);
    float excl2 = base + ws - run;
#pragma unroll
    for (int k = 0; k < 8; k++) {
        int t = tid * 8 + k;
        cs[CSI(t)] = excl2 + ((k == 0) ? 0.0f : r[k - 1]);
    }
    if (tid == 511) cs[CSI(LL)] = grand2;
    __syncthreads();                           // B6

    // ---- box smooth (cyclic t: conflict-free cs reads; result in place) ----
    const int wh = w / 2;
    const float invw = 1.0f / (float)w;
#pragma unroll
    for (int k = 0; k < 8; k++) {
        int t  = tid + 512 * k;
        int li = t - wh;
        int hi = li + w;
        li = (li < 0) ? 0 : li;
        hi = (hi > LL) ? LL : hi;
        r[k] = (cs[CSI(hi)] - cs[CSI(li)]) * invw;
    }
    if (tid == 0)   shv[0] = r[0];      // b[0]   (t = 0)
    if (tid == 511) shv[1] = r[7];      // b[L-1] (t = 4095)
    __syncthreads();                           // B7
    const float b0 = shv[0], bL = shv[1];

    // ---- detrend #2 + absmax-normalize ----
    float am = 0.0f;
#pragma unroll
    for (int k = 0; k < 8; k++) {
        int t = tid + 512 * k;
        r[k] -= b0 + (bL - b0) * ((float)t * inv_nm1);
        am = fmaxf(am, fabsf(r[k]));
    }
#pragma unroll
    for (int off = 32; off > 0; off >>= 1) am = fmaxf(am, __shfl_xor(am, off));
    if (lane == 0) tmp[wid] = am;
    __syncthreads();                           // B8
    float denom = fmaxf(fmaxf(fmaxf(tmp[0],tmp[1]),fmaxf(tmp[2],tmp[3])),
                        fmaxf(fmaxf(tmp[4],tmp[5]),fmaxf(tmp[6],tmp[7])));
    denom = (denom == 0.0f) ? 1.0f : denom;
    const float fac = g_omit[n] * g_scale[n] / denom;
    __syncthreads();                           // B9 (all tmp reads done)

    // ---- stash bb row at bf[t] (overwrites cs; cs reads completed at B7) ----
#pragma unroll
    for (int k = 0; k < 8; k++) {
        int t = tid + 512 * k;
        bf[t] = r[k] * fac;
    }
    __syncthreads();                           // B10

    // ---- interp bb onto ppm axis -> X[8] registers (= pass-1 butterfly inputs) ----
    const float xlo = g_ppmr[0];
    const float xhi = g_ppmr[1];
    const float posmul = (float)(LL - 1) / (xhi - xlo);
    const size_t base1 = (size_t)NB * 2 * PP + (size_t)n * 2 * PP;  // raw
    const size_t base0 = (size_t)n * 2 * PP;                        // flipped

    auto interp1 = [&](float x) -> float {
        if (x < xlo || x > xhi) return 0.0f;
        float pos = (x - xlo) * posmul;
        int idx = (int)floorf(pos);
        idx = (idx < 0) ? 0 : ((idx > LL - 2) ? (LL - 2) : idx);
        float fr = pos - (float)idx;
        float s0 = bf[idx], s1 = bf[idx + 1];
        return s0 + (s1 - s0) * fr;
    };

    float2 X[8];
#pragma unroll
    for (int m = 0; m < 8; m++) {
        int p = tid + 512 * m;
        float2 pm = *(const float2*)(g_ppm + 2 * p);
        float re0 = interp1(pm.x);
        float re1 = interp1(pm.y);
        X[m] = make_float2(re0, re1);
        *(float2*)(g_out + base1 + 2 * p)          = make_float2(re0, re1);   // raw real
        *(float2*)(g_out + base0 + PP - 2 - 2 * p) = make_float2(re1, re0);   // flipped real
    }
    __syncthreads();                           // B11 (all bb reads complete)

    // ===== forward FFT: 4 radix-8 DIF passes (H = 512, 64, 8, 1) =====
    const int bA = tid + 2 * (tid >> 4);                 // PH2(tid); offsets 576*r
    {
        // pass 1 (H=512): inputs already in X (p = tid + 512d)
        core8f(X);
        float sn, cn; __sincosf((-PIF / 2048.0f) * (float)tid, &sn, &cn);
        float2 E = make_float2(cn, sn), Er = E;
        buf[bA]        = X[0];
        buf[bA +  576] = cmul(X[1], Er); Er = cmul(Er, E);
        buf[bA + 1152] = cmul(X[2], Er); Er = cmul(Er, E);
        buf[bA + 1728] = cmul(X[3], Er); Er = cmul(Er, E);
        buf[bA + 2304] = cmul(X[4], Er); Er = cmul(Er, E);
        buf[bA + 2880] = cmul(X[5], Er); Er = cmul(Er, E);
        buf[bA + 3456] = cmul(X[6], Er); Er = cmul(Er, E);
        buf[bA + 4032] = cmul(X[7], Er);
    }
    __syncthreads();                           // B12

    const int j2 = tid & 63;
    const int bB = (tid >> 6) * 576 + j2 + 2 * (j2 >> 4);   // offsets 72*r
    {
        // pass 2 (H=64)
#pragma unroll
        for (int d = 0; d < 8; d++) X[d] = buf[bB + 72 * d];
        core8f(X);
        float sn, cn; __sincosf((-PIF / 256.0f) * (float)j2, &sn, &cn);
        float2 E = make_float2(cn, sn), Er = E;
        buf[bB]       = X[0];
        buf[bB +  72] = cmul(X[1], Er); Er = cmul(Er, E);
        buf[bB + 144] = cmul(X[2], Er); Er = cmul(Er, E);
        buf[bB + 216] = cmul(X[3], Er); Er = cmul(Er, E);
        buf[bB + 288] = cmul(X[4], Er); Er = cmul(Er, E);
        buf[bB + 360] = cmul(X[5], Er); Er = cmul(Er, E);
        buf[bB + 432] = cmul(X[6], Er); Er = cmul(Er, E);
        buf[bB + 504] = cmul(X[7], Er);
    }
    __syncthreads();                           // B13

    const int j3 = tid & 7;
    const int bC = (tid >> 3) * 72 + j3;       // offsets 8d + 2*(d>>1): 0,8,18,26,36,44,54,62
    {
        // pass 3 (H=8)
        X[0]=buf[bC];    X[1]=buf[bC+8];  X[2]=buf[bC+18]; X[3]=buf[bC+26];
        X[4]=buf[bC+36]; X[5]=buf[bC+44]; X[6]=buf[bC+54]; X[7]=buf[bC+62];
        core8f(X);
        float sn, cn; __sincosf((-PIF / 32.0f) * (float)j3, &sn, &cn);
        float2 E = make_float2(cn, sn), Er = E;
        buf[bC]    = X[0];
        buf[bC+ 8] = cmul(X[1], Er); Er = cmul(Er, E);
        buf[bC+18] = cmul(X[2], Er); Er = cmul(Er, E);
        buf[bC+26] = cmul(X[3], Er); Er = cmul(Er, E);
        buf[bC+36] = cmul(X[4], Er); Er = cmul(Er, E);
        buf[bC+44] = cmul(X[5], Er); Er = cmul(Er, E);
        buf[bC+54] = cmul(X[6], Er); Er = cmul(Er, E);
        buf[bC+62] = cmul(X[7], Er);
    }
    __syncthreads();                           // B14

    const int f4 = 4 * tid + (tid >> 1);       // float4 index of PH2(8*tid)/2
    float4* b4 = reinterpret_cast<float4*>(buf);
    {
        // pass 4 (H=1, twiddle-free), contiguous b128
        float4 a0 = b4[f4], a1 = b4[f4+1], a2 = b4[f4+2], a3 = b4[f4+3];
        X[0]=make_float2(a0.x,a0.y); X[1]=make_float2(a0.z,a0.w);
        X[2]=make_float2(a1.x,a1.y); X[3]=make_float2(a1.z,a1.w);
        X[4]=make_float2(a2.x,a2.y); X[5]=make_float2(a2.z,a2.w);
        X[6]=make_float2(a3.x,a3.y); X[7]=make_float2(a3.z,a3.w);
        core8f(X);
        b4[f4]   = make_float4(X[0].x,X[0].y,X[1].x,X[1].y);
        b4[f4+1] = make_float4(X[2].x,X[2].y,X[3].x,X[3].y);
        b4[f4+2] = make_float4(X[4].x,X[4].y,X[5].x,X[5].y);
        b4[f4+3] = make_float4(X[6].x,X[6].y,X[7].x,X[7].y);
    }
    __syncthreads();                           // B15

    // ===== Hilbert pair-fix: buf[PH2(rev8(k))] = Z[k] -> Z'[k], 4 pairs/thread =====
    {
        const float s = 1.0f / (2.0f * (float)FN);
#pragma unroll
        for (int m = 0; m < 4; m++) {
            int k = ((tid & 31) << 6) | ((tid >> 5) << 2) | m;   // k in [0,2047]
            if (k == 0) {
                buf[0] = make_float2(0.0f, 0.0f);                // k=0 (rev8(0)=0)
                float2 Z = buf[4];                               // k=2048: rev8=4, self-pair
                buf[4] = make_float2(-2.0f*s*Z.y, 2.0f*s*Z.x);
            } else {
                int pk = PH2(rev8(k));
                int pj = PH2(rev8(FN - k));
                float2 Zk = buf[pk];
                float2 Zj = buf[pj];
                float ux = Zk.x + Zj.x, uy = Zk.y - Zj.y;        // u = Zk + conj(Zj)
                float vx = Zk.x - Zj.x, vy = Zk.y + Zj.y;        // v = Zk - conj(Zj)
                float sn, cn; __sincosf((PIF/(float)FN) * (float)k, &sn, &cn);  // conj(W)
                float2 zk, zj;
                zk.x = s * ((ux*cn - uy*sn) - (vx*cn + vy*sn));
                zk.y = s * ((ux*sn + uy*cn) + (vx*sn - vy*cn));
                float u2x = ux,  u2y = -uy;
                float v2x = -vx, v2y = vy;
                zj.x = s * ((v2x*cn - v2y*sn) - (u2x*cn + u2y*sn));
                zj.y = s * ((v2x*sn + v2y*cn) + (u2x*sn - u2y*cn));
                buf[pk] = zk;
                buf[pj] = zj;
            }
        }
    }
    __syncthreads();                           // B16

    // ===== inverse FFT: 4 radix-8 DIT passes (H = 1, 8, 64, 512) =====
    {
        // pass 1' (H=1, twiddle-free)
        float4 a0 = b4[f4], a1 = b4[f4+1], a2 = b4[f4+2], a3 = b4[f4+3];
        X[0]=make_float2(a0.x,a0.y); X[1]=make_float2(a0.z,a0.w);
        X[2]=make_float2(a1.x,a1.y); X[3]=make_float2(a1.z,a1.w);
        X[4]=make_float2(a2.x,a2.y); X[5]=make_float2(a2.z,a2.w);
        X[6]=make_float2(a3.x,a3.y); X[7]=make_float2(a3.z,a3.w);
        core8i(X);
        b4[f4]   = make_float4(X[0].x,X[0].y,X[1].x,X[1].y);
        b4[f4+1] = make_float4(X[2].x,X[2].y,X[3].x,X[3].y);
        b4[f4+2] = make_float4(X[4].x,X[4].y,X[5].x,X[5].y);
        b4[f4+3] = make_float4(X[6].x,X[6].y,X[7].x,X[7].y);
    }
    __syncthreads();                           // B17

    {
        // pass 2' (H=8): conj twiddle on inputs, then inverse core
        X[0]=buf[bC];    X[1]=buf[bC+8];  X[2]=buf[bC+18]; X[3]=buf[bC+26];
        X[4]=buf[bC+36]; X[5]=buf[bC+44]; X[6]=buf[bC+54]; X[7]=buf[bC+62];
        float sn, cn; __sincosf((PIF / 32.0f) * (float)j3, &sn, &cn);
        float2 E = make_float2(cn, sn), Er = E;
        X[1]=cmul(X[1],Er); Er=cmul(Er,E);
        X[2]=cmul(X[2],Er); Er=cmul(Er,E);
        X[3]=cmul(X[3],Er); Er=cmul(Er,E);
        X[4]=cmul(X[4],Er); Er=cmul(Er,E);
        X[5]=cmul(X[5],Er); Er=cmul(Er,E);
        X[6]=cmul(X[6],Er); Er=cmul(Er,E);
        X[7]=cmul(X[7],Er);
        core8i(X);
        buf[bC]=X[0];    buf[bC+8]=X[1];  buf[bC+18]=X[2]; buf[bC+26]=X[3];
        buf[bC+36]=X[4]; buf[bC+44]=X[5]; buf[bC+54]=X[6]; buf[bC+62]=X[7];
    }
    __syncthreads();                           // B18

    {
        // pass 3' (H=64)
#pragma unroll
        for (int d = 0; d < 8; d++) X[d] = buf[bB + 72 * d];
        float sn, cn; __sincosf((PIF / 256.0f) * (float)j2, &sn, &cn);
        float2 E = make_float2(cn, sn), Er = E;
        X[1]=cmul(X[1],Er); Er=cmul(Er,E);
        X[2]=cmul(X[2],Er); Er=cmul(Er,E);
        X[3]=cmul(X[3],Er); Er=cmul(Er,E);
        X[4]=cmul(X[4],Er); Er=cmul(Er,E);
        X[5]=cmul(X[5],Er); Er=cmul(Er,E);
        X[6]=cmul(X[6],Er); Er=cmul(Er,E);
        X[7]=cmul(X[7],Er);
        core8i(X);
#pragma unroll
        for (int d = 0; d < 8; d++) buf[bB + 72 * d] = X[d];
    }
    __syncthreads();                           // B19

    {
        // pass 4' (H=512): final; outputs go straight to global imag planes
#pragma unroll
        for (int d = 0; d < 8; d++) X[d] = buf[bA + 576 * d];
        float sn, cn; __sincosf((PIF / 2048.0f) * (float)tid, &sn, &cn);
        float2 E = make_float2(cn, sn), Er = E;
        X[1]=cmul(X[1],Er); Er=cmul(Er,E);
        X[2]=cmul(X[2],Er); Er=cmul(Er,E);
        X[3]=cmul(X[3],Er); Er=cmul(Er,E);
        X[4]=cmul(X[4],Er); Er=cmul(Er,E);
        X[5]=cmul(X[5],Er); Er=cmul(Er,E);
        X[6]=cmul(X[6],Er); Er=cmul(Er,E);
        X[7]=cmul(X[7],Er);
        core8i(X);
        // X[d] = (Hx[2p], Hx[2p+1]), p = tid + 512d
#pragma unroll
        for (int d = 0; d < 8; d++) {
            int p = tid + 512 * d;
            float2 vv = X[d];
            *(float2*)(g_out + base1 + PP + 2 * p)         = vv;                        // raw imag
            *(float2*)(g_out + base0 + 2 * PP - 2 - 2 * p) = make_float2(vv.y, vv.x);   // flipped imag
        }
    }
}

extern "C" void kernel_launch(void* const* d_in, const int* in_sizes, int n_in,
                              void* d_out, int out_size, void* d_ws, size_t ws_size,
                              hipStream_t stream)
{
    const float* start = (const float*)d_in[0];
    const float* end_  = (const float*)d_in[1];
    const float* stdv  = (const float*)d_in[2];
    const float* lowb  = (const float*)d_in[3];
    const float* upb   = (const float*)d_in[4];
    const int*   win   = (const int*)d_in[5];
    const float* scl   = (const float*)d_in[6];
    const float* noise = (const float*)d_in[7];
    const float* omit  = (const float*)d_in[8];
    const float* ppm   = (const float*)d_in[9];
    const float* ppmr  = (const float*)d_in[10];
    float* out = (float*)d_out;

    hipLaunchKernelGGL(k_all, dim3(NB), dim3(512), 0, stream,
                       start, end_, stdv, lowb, upb, win, scl, noise, omit,
                       ppm, ppmr, out);
}

// Round 7
// 174.281 us; speedup vs baseline: 1.0817x; 1.0090x over previous
//
#include <hip/hip_runtime.h>

#define NB 1024
#define LL 4096
#define PP 8192
#define FN 4096            // complex FFT length = PP/2 (real-packed Hilbert)

#define PIF 3.14159265358979323846f

__device__ __forceinline__ float2 cadd(float2 a, float2 b){ return make_float2(a.x+b.x, a.y+b.y); }
__device__ __forceinline__ float2 csub(float2 a, float2 b){ return make_float2(a.x-b.x, a.y-b.y); }
__device__ __forceinline__ float2 cmul(float2 a, float2 b){ return make_float2(a.x*b.x - a.y*b.y, a.x*b.y + a.y*b.x); }

// wave-local fence: no s_barrier, just forbid compiler reordering across it.
// Used between FFT passes where each wave touches only its own 576-float2 block.
#define WFENCE() do { __builtin_amdgcn_wave_barrier(); asm volatile("" ::: "memory"); } while (0)

// additive LDS pad on the float2 index: bijective, compile-time ds offsets per pass
__device__ __forceinline__ int PH2(int p){ return p + 2*(p >> 4); }

// base-8 digit reversal of a 12-bit index (4 digits) — radix-8 DIF output permutation
__device__ __forceinline__ int rev8(int k){
    return ((k & 7) << 9) | (((k >> 3) & 7) << 6) | (((k >> 6) & 7) << 3) | ((k >> 9) & 7);
}

// ---- radix-8 DFT core, forward (in place, time order in -> freq order r out) ----
__device__ __forceinline__ void core8f(float2* x){
    const float c8 = 0.70710678118654752f;
    float2 e0=cadd(x[0],x[4]), e1=cadd(x[1],x[5]), e2=cadd(x[2],x[6]), e3=cadd(x[3],x[7]);
    float2 o0=csub(x[0],x[4]), o1=csub(x[1],x[5]), o2=csub(x[2],x[6]), o3=csub(x[3],x[7]);
    float2 t1 = make_float2(c8*(o1.x + o1.y), c8*(o1.y - o1.x));   // o1*w8^1, w8=(c,-c)
    float2 t2 = make_float2(o2.y, -o2.x);                          // o2*(-i)
    float2 t3 = make_float2(c8*(o3.y - o3.x), -c8*(o3.x + o3.y));  // o3*w8^3=(-c,-c)
    float2 a0=cadd(e0,e2), a1=cadd(e1,e3), a2=csub(e0,e2), a3=csub(e1,e3);
    x[0]=cadd(a0,a1); x[4]=csub(a0,a1);
    x[2]=make_float2(a2.x + a3.y, a2.y - a3.x);                    // a2 - i a3
    x[6]=make_float2(a2.x - a3.y, a2.y + a3.x);
    float2 b0=cadd(o0,t2), b1=cadd(t1,t3), b2=csub(o0,t2), b3=csub(t1,t3);
    x[1]=cadd(b0,b1); x[5]=csub(b0,b1);
    x[3]=make_float2(b2.x + b3.y, b2.y - b3.x);
    x[7]=make_float2(b2.x - b3.y, b2.y + b3.x);
}
// ---- radix-8 core, inverse/conjugate (unnormalized IDFT) ----
__device__ __forceinline__ void core8i(float2* x){
    const float c8 = 0.70710678118654752f;
    float2 e0=cadd(x[0],x[4]), e1=cadd(x[1],x[5]), e2=cadd(x[2],x[6]), e3=cadd(x[3],x[7]);
    float2 o0=csub(x[0],x[4]), o1=csub(x[1],x[5]), o2=csub(x[2],x[6]), o3=csub(x[3],x[7]);
    float2 t1 = make_float2(c8*(o1.x - o1.y), c8*(o1.y + o1.x));   // o1*(c, c)
    float2 t2 = make_float2(-o2.y, o2.x);                          // o2*(+i)
    float2 t3 = make_float2(-c8*(o3.x + o3.y), c8*(o3.x - o3.y));  // o3*(-c, c)
    float2 a0=cadd(e0,e2), a1=cadd(e1,e3), a2=csub(e0,e2), a3=csub(e1,e3);
    x[0]=cadd(a0,a1); x[4]=csub(a0,a1);
    x[2]=make_float2(a2.x - a3.y, a2.y + a3.x);                    // a2 + i a3
    x[6]=make_float2(a2.x + a3.y, a2.y - a3.x);
    float2 b0=cadd(o0,t2), b1=cadd(t1,t3), b2=csub(o0,t2), b3=csub(t1,t3);
    x[1]=cadd(b0,b1); x[5]=csub(b0,b1);
    x[3]=make_float2(b2.x - b3.y, b2.y + b3.x);
    x[7]=make_float2(b2.x + b3.y, b2.y - b3.x);
}

__global__ __launch_bounds__(512, 8) void k_all(
    const float* __restrict__ g_start,
    const float* __restrict__ g_end,
    const float* __restrict__ g_std,
    const float* __restrict__ g_low,
    const float* __restrict__ g_up,
    const int*   __restrict__ g_win,
    const float* __restrict__ g_scale,
    const float* __restrict__ g_noise,
    const float* __restrict__ g_omit,
    const float* __restrict__ g_ppm,
    const float* __restrict__ g_ppmr,
    float* __restrict__ g_out)
{
    __shared__ alignas(16) float2 buf[4608];   // 36 KB -> 4 blocks/CU (32 waves/CU)
    float* bf  = (float*)buf;                  // 9216 floats
#define CSI(t) ((t) + ((t) >> 5))
    float* cs   = bf;                          // CSI(0..4096) -> 0..4224
    float* tmp1 = bf + 4226;                   // 8  (scan #1 wave partials)
    float* tmp2 = bf + 4240;                   // 16 (minmax wave partials)
    float* tmp3 = bf + 4256;                   // 8  (scan #2 wave partials)
    float* tmp4 = bf + 4264;                   // 8  (absmax wave partials)
    float* shv  = bf + 4272;                   // 1  (rand[0])

    const int n    = blockIdx.x;
    const int tid  = threadIdx.x;
    const int lane = tid & 63;
    const int wid  = tid >> 6;                 // 8 waves / block
    const float st = g_start[n];
    const float en = g_end[n];
    const float sd = g_std[n];
    const float lo = g_low[n];
    const float up = g_up[n];
    const int   w  = g_win[n];
    const float inv_nm1 = 1.0f / (float)(LL - 1);

    // ---- load 8 fp32 noise steps/thread ----
    float r[8];
    {
        const float4* p = (const float4*)(g_noise + (size_t)n * LL) + (size_t)tid * 2;
        float4 ta = p[0], tb = p[1];
        r[0]=ta.x; r[1]=ta.y; r[2]=ta.z; r[3]=ta.w;
        r[4]=tb.x; r[5]=tb.y; r[6]=tb.z; r[7]=tb.w;
    }
#pragma unroll
    for (int k = 0; k < 8; k++) r[k] = sd * (r[k] - 0.5f);

    // ---- scan #1 (rand = inclusive cumsum) ----
    float run = 0.0f;
#pragma unroll
    for (int k = 0; k < 8; k++) { run += r[k]; r[k] = run; }
    float ws = run;
#pragma unroll
    for (int off = 1; off < 64; off <<= 1) { float t = __shfl_up(ws, off); if (lane >= off) ws += t; }
    if (lane == 63) tmp1[wid] = ws;
    if (tid == 0)   shv[0] = r[0];             // rand[0]
    __syncthreads();                           // B1
    float t0=tmp1[0],t1=tmp1[1],t2=tmp1[2],t3=tmp1[3],t4=tmp1[4],t5=tmp1[5],t6=tmp1[6],t7=tmp1[7];
    const float rT = ((t0+t1)+(t2+t3))+((t4+t5)+(t6+t7));
    const float r0 = shv[0];
    float base = (wid>0?t0:0.f)+(wid>1?t1:0.f)+(wid>2?t2:0.f)+(wid>3?t3:0.f)
               + (wid>4?t4:0.f)+(wid>5?t5:0.f)+(wid>6?t6:0.f);
    float excl = base + ws - run;
    // (no barrier: next phase writes tmp2, disjoint from tmp1/shv)

    // ---- detrend walk (in place), min/max ----
    float mx = -INFINITY, mn = INFINITY;
#pragma unroll
    for (int k = 0; k < 8; k++) {
        int t = tid * 8 + k;
        float d = (excl + r[k]) - (r0 + (rT - r0) * ((float)t * inv_nm1));
        r[k] = d;
        mx = fmaxf(mx, d); mn = fminf(mn, d);
    }
#pragma unroll
    for (int off = 32; off > 0; off >>= 1) {
        mx = fmaxf(mx, __shfl_xor(mx, off));
        mn = fminf(mn, __shfl_xor(mn, off));
    }
    if (lane == 0) { tmp2[wid] = mx; tmp2[8 + wid] = mn; }
    __syncthreads();                           // B3
    mx = fmaxf(fmaxf(fmaxf(tmp2[0],tmp2[1]),fmaxf(tmp2[2],tmp2[3])),
               fmaxf(fmaxf(tmp2[4],tmp2[5]),fmaxf(tmp2[6],tmp2[7])));
    mn = fminf(fminf(fminf(tmp2[8],tmp2[9]),fminf(tmp2[10],tmp2[11])),
               fminf(fminf(tmp2[12],tmp2[13]),fminf(tmp2[14],tmp2[15])));
    // (no barrier: next scan writes tmp3, disjoint from tmp2)

    const float qs = fmaxf(1.0f, (mx - mn) / (up - lo));

    // ---- squeeze + reflect + trend -> walk values (in place) ----
#pragma unroll
    for (int k = 0; k < 8; k++) {
        int t = tid * 8 + k;
        float tr  = st + (en - st) * ((float)t * inv_nm1);
        float ub  = up - tr;
        float lb2 = lo - tr;
        float d = r[k] / qs;
        float over = d - ub;
        d = (over >= 0.0f) ? (ub - over) : d;
        float under = lb2 - d;
        d = (under >= 0.0f) ? (lb2 + under) : d;
        r[k] = tr + d;
    }

    // ---- scan #2: exclusive cumsum of walk -> cs[CSI(0..LL)] ----
    run = 0.0f;
#pragma unroll
    for (int k = 0; k < 8; k++) { run += r[k]; r[k] = run; }
    ws = run;
#pragma unroll
    for (int off = 1; off < 64; off <<= 1) { float t = __shfl_up(ws, off); if (lane >= off) ws += t; }
    if (lane == 63) tmp3[wid] = ws;
    __syncthreads();                           // B5
    t0=tmp3[0];t1=tmp3[1];t2=tmp3[2];t3=tmp3[3];t4=tmp3[4];t5=tmp3[5];t6=tmp3[6];t7=tmp3[7];
    const float grand2 = ((t0+t1)+(t2+t3))+((t4+t5)+(t6+t7));
    base = (wid>0?t0:0.f)+(wid>1?t1:0.f)+(wid>2?t2:0.f)+(wid>3?t3:0.f)
         + (wid>4?t4:0.f)+(wid>5?t5:0.f)+(wid>6?t6:0.f);
    float excl2 = base + ws - run;
#pragma unroll
    for (int k = 0; k < 8; k++) {
        int t = tid * 8 + k;
        cs[CSI(t)] = excl2 + ((k == 0) ? 0.0f : r[k - 1]);
    }
    if (tid == 511) cs[CSI(LL)] = grand2;
    __syncthreads();                           // B6

    // ---- box smooth (cyclic t: conflict-free cs reads; result in place) ----
    const int wh = w / 2;
    const float invw = 1.0f / (float)w;
#pragma unroll
    for (int k = 0; k < 8; k++) {
        int t  = tid + 512 * k;
        int li = t - wh;
        int hi = li + w;
        li = (li < 0) ? 0 : li;
        hi = (hi > LL) ? LL : hi;
        r[k] = (cs[CSI(hi)] - cs[CSI(li)]) * invw;
    }
    // b[0], b[L-1] recomputed per-thread from cs (broadcast reads) — no barrier.
    float b0v, bLv;
    {
        int hi0 = w - wh;                                  // t=0: li=0
        b0v = (cs[CSI(hi0)] - cs[CSI(0)]) * invw;
        int liL = LL - 1 - wh;
        int hiL = liL + w; if (hiL > LL) hiL = LL;         // t=LL-1
        bLv = (cs[CSI(hiL)] - cs[CSI(liL)]) * invw;
    }

    // ---- detrend #2 + absmax-normalize ----
    float am = 0.0f;
#pragma unroll
    for (int k = 0; k < 8; k++) {
        int t = tid + 512 * k;
        r[k] -= b0v + (bLv - b0v) * ((float)t * inv_nm1);
        am = fmaxf(am, fabsf(r[k]));
    }
#pragma unroll
    for (int off = 32; off > 0; off >>= 1) am = fmaxf(am, __shfl_xor(am, off));
    if (lane == 0) tmp4[wid] = am;
    __syncthreads();                           // B8 (also orders cs reads before bf writes)
    float denom = fmaxf(fmaxf(fmaxf(tmp4[0],tmp4[1]),fmaxf(tmp4[2],tmp4[3])),
                        fmaxf(fmaxf(tmp4[4],tmp4[5]),fmaxf(tmp4[6],tmp4[7])));
    denom = (denom == 0.0f) ? 1.0f : denom;
    const float fac = g_omit[n] * g_scale[n] / denom;

    // ---- stash bb row at bf[t] (overwrites cs; all cs reads done pre-B8;
    //      bf[0..4095] is disjoint from tmp4 @4264+) ----
#pragma unroll
    for (int k = 0; k < 8; k++) {
        int t = tid + 512 * k;
        bf[t] = r[k] * fac;
    }
    __syncthreads();                           // B10

    // ---- interp bb onto ppm axis -> X[8] registers (= pass-1 butterfly inputs) ----
    const float xlo = g_ppmr[0];
    const float xhi = g_ppmr[1];
    const float posmul = (float)(LL - 1) / (xhi - xlo);
    const size_t base1 = (size_t)NB * 2 * PP + (size_t)n * 2 * PP;  // raw
    const size_t base0 = (size_t)n * 2 * PP;                        // flipped

    auto interp1 = [&](float x) -> float {
        if (x < xlo || x > xhi) return 0.0f;
        float pos = (x - xlo) * posmul;
        int idx = (int)floorf(pos);
        idx = (idx < 0) ? 0 : ((idx > LL - 2) ? (LL - 2) : idx);
        float fr = pos - (float)idx;
        float s0 = bf[idx], s1 = bf[idx + 1];
        return s0 + (s1 - s0) * fr;
    };

    float2 X[8];
#pragma unroll
    for (int m = 0; m < 8; m++) {
        int p = tid + 512 * m;
        float2 pm = *(const float2*)(g_ppm + 2 * p);
        float re0 = interp1(pm.x);
        float re1 = interp1(pm.y);
        X[m] = make_float2(re0, re1);
        *(float2*)(g_out + base1 + 2 * p)          = make_float2(re0, re1);   // raw real
        *(float2*)(g_out + base0 + PP - 2 - 2 * p) = make_float2(re1, re0);   // flipped real
    }
    __syncthreads();                           // B11 (all bb reads complete)

    // ===== forward FFT: 4 radix-8 DIF passes (H = 512, 64, 8, 1) =====
    // Pass 1 mixes across the whole array (needs barriers). Passes 2-4 are
    // wave-local: wave w touches exactly padded block [576w, 576w+576).
    const int bA = tid + 2 * (tid >> 4);                 // PH2(tid); offsets 576*r
    {
        // pass 1 (H=512): inputs already in X (p = tid + 512d)
        core8f(X);
        float sn, cn; __sincosf((-PIF / 2048.0f) * (float)tid, &sn, &cn);
        float2 E = make_float2(cn, sn), Er = E;
        buf[bA]        = X[0];
        buf[bA +  576] = cmul(X[1], Er); Er = cmul(Er, E);
        buf[bA + 1152] = cmul(X[2], Er); Er = cmul(Er, E);
        buf[bA + 1728] = cmul(X[3], Er); Er = cmul(Er, E);
        buf[bA + 2304] = cmul(X[4], Er); Er = cmul(Er, E);
        buf[bA + 2880] = cmul(X[5], Er); Er = cmul(Er, E);
        buf[bA + 3456] = cmul(X[6], Er); Er = cmul(Er, E);
        buf[bA + 4032] = cmul(X[7], Er);
    }
    __syncthreads();                           // B12

    const int j2 = tid & 63;
    const int bB = (tid >> 6) * 576 + j2 + 2 * (j2 >> 4);   // offsets 72*r
    {
        // pass 2 (H=64) — wave-local
#pragma unroll
        for (int d = 0; d < 8; d++) X[d] = buf[bB + 72 * d];
        core8f(X);
        float sn, cn; __sincosf((-PIF / 256.0f) * (float)j2, &sn, &cn);
        float2 E = make_float2(cn, sn), Er = E;
        buf[bB]       = X[0];
        buf[bB +  72] = cmul(X[1], Er); Er = cmul(Er, E);
        buf[bB + 144] = cmul(X[2], Er); Er = cmul(Er, E);
        buf[bB + 216] = cmul(X[3], Er); Er = cmul(Er, E);
        buf[bB + 288] = cmul(X[4], Er); Er = cmul(Er, E);
        buf[bB + 360] = cmul(X[5], Er); Er = cmul(Er, E);
        buf[bB + 432] = cmul(X[6], Er); Er = cmul(Er, E);
        buf[bB + 504] = cmul(X[7], Er);
    }
    WFENCE();                                  // wave-local: no block barrier

    const int j3 = tid & 7;
    const int bC = (tid >> 3) * 72 + j3;       // offsets 8d + 2*(d>>1): 0,8,18,26,36,44,54,62
    {
        // pass 3 (H=8) — wave-local
        X[0]=buf[bC];    X[1]=buf[bC+8];  X[2]=buf[bC+18]; X[3]=buf[bC+26];
        X[4]=buf[bC+36]; X[5]=buf[bC+44]; X[6]=buf[bC+54]; X[7]=buf[bC+62];
        core8f(X);
        float sn, cn; __sincosf((-PIF / 32.0f) * (float)j3, &sn, &cn);
        float2 E = make_float2(cn, sn), Er = E;
        buf[bC]    = X[0];
        buf[bC+ 8] = cmul(X[1], Er); Er = cmul(Er, E);
        buf[bC+18] = cmul(X[2], Er); Er = cmul(Er, E);
        buf[bC+26] = cmul(X[3], Er); Er = cmul(Er, E);
        buf[bC+36] = cmul(X[4], Er); Er = cmul(Er, E);
        buf[bC+44] = cmul(X[5], Er); Er = cmul(Er, E);
        buf[bC+54] = cmul(X[6], Er); Er = cmul(Er, E);
        buf[bC+62] = cmul(X[7], Er);
    }
    WFENCE();                                  // wave-local

    const int f4 = 4 * tid + (tid >> 1);       // float4 index of PH2(8*tid)/2
    float4* b4 = reinterpret_cast<float4*>(buf);
    {
        // pass 4 (H=1, twiddle-free), contiguous b128 — wave-local
        float4 a0 = b4[f4], a1 = b4[f4+1], a2 = b4[f4+2], a3 = b4[f4+3];
        X[0]=make_float2(a0.x,a0.y); X[1]=make_float2(a0.z,a0.w);
        X[2]=make_float2(a1.x,a1.y); X[3]=make_float2(a1.z,a1.w);
        X[4]=make_float2(a2.x,a2.y); X[5]=make_float2(a2.z,a2.w);
        X[6]=make_float2(a3.x,a3.y); X[7]=make_float2(a3.z,a3.w);
        core8f(X);
        b4[f4]   = make_float4(X[0].x,X[0].y,X[1].x,X[1].y);
        b4[f4+1] = make_float4(X[2].x,X[2].y,X[3].x,X[3].y);
        b4[f4+2] = make_float4(X[4].x,X[4].y,X[5].x,X[5].y);
        b4[f4+3] = make_float4(X[6].x,X[6].y,X[7].x,X[7].y);
    }
    __syncthreads();                           // B15 (Hilbert pairs cross blocks)

    // ===== Hilbert pair-fix: buf[PH2(rev8(k))] = Z[k] -> Z'[k], 4 pairs/thread =====
    {
        const float s = 1.0f / (2.0f * (float)FN);
#pragma unroll
        for (int m = 0; m < 4; m++) {
            int k = ((tid & 31) << 6) | ((tid >> 5) << 2) | m;   // k in [0,2047]
            if (k == 0) {
                buf[0] = make_float2(0.0f, 0.0f);                // k=0 (rev8(0)=0)
                float2 Z = buf[4];                               // k=2048: rev8=4, self-pair
                buf[4] = make_float2(-2.0f*s*Z.y, 2.0f*s*Z.x);
            } else {
                int pk = PH2(rev8(k));
                int pj = PH2(rev8(FN - k));
                float2 Zk = buf[pk];
                float2 Zj = buf[pj];
                float ux = Zk.x + Zj.x, uy = Zk.y - Zj.y;        // u = Zk + conj(Zj)
                float vx = Zk.x - Zj.x, vy = Zk.y + Zj.y;        // v = Zk - conj(Zj)
                float sn, cn; __sincosf((PIF/(float)FN) * (float)k, &sn, &cn);  // conj(W)
                float2 zk, zj;
                zk.x = s * ((ux*cn - uy*sn) - (vx*cn + vy*sn));
                zk.y = s * ((ux*sn + uy*cn) + (vx*sn - vy*cn));
                float u2x = ux,  u2y = -uy;
                float v2x = -vx, v2y = vy;
                zj.x = s * ((v2x*cn - v2y*sn) - (u2x*cn + u2y*sn));
                zj.y = s * ((v2x*sn + v2y*cn) + (u2x*sn - u2y*cn));
                buf[pk] = zk;
                buf[pj] = zj;
            }
        }
    }
    __syncthreads();                           // B16

    // ===== inverse FFT: 4 radix-8 DIT passes (H = 1, 8, 64, 512) =====
    {
        // pass 1' (H=1, twiddle-free) — wave-local
        float4 a0 = b4[f4], a1 = b4[f4+1], a2 = b4[f4+2], a3 = b4[f4+3];
        X[0]=make_float2(a0.x,a0.y); X[1]=make_float2(a0.z,a0.w);
        X[2]=make_float2(a1.x,a1.y); X[3]=make_float2(a1.z,a1.w);
        X[4]=make_float2(a2.x,a2.y); X[5]=make_float2(a2.z,a2.w);
        X[6]=make_float2(a3.x,a3.y); X[7]=make_float2(a3.z,a3.w);
        core8i(X);
        b4[f4]   = make_float4(X[0].x,X[0].y,X[1].x,X[1].y);
        b4[f4+1] = make_float4(X[2].x,X[2].y,X[3].x,X[3].y);
        b4[f4+2] = make_float4(X[4].x,X[4].y,X[5].x,X[5].y);
        b4[f4+3] = make_float4(X[6].x,X[6].y,X[7].x,X[7].y);
    }
    WFENCE();                                  // wave-local

    {
        // pass 2' (H=8): conj twiddle on inputs, then inverse core — wave-local
        X[0]=buf[bC];    X[1]=buf[bC+8];  X[2]=buf[bC+18]; X[3]=buf[bC+26];
        X[4]=buf[bC+36]; X[5]=buf[bC+44]; X[6]=buf[bC+54]; X[7]=buf[bC+62];
        float sn, cn; __sincosf((PIF / 32.0f) * (float)j3, &sn, &cn);
        float2 E = make_float2(cn, sn), Er = E;
        X[1]=cmul(X[1],Er); Er=cmul(Er,E);
        X[2]=cmul(X[2],Er); Er=cmul(Er,E);
        X[3]=cmul(X[3],Er); Er=cmul(Er,E);
        X[4]=cmul(X[4],Er); Er=cmul(Er,E);
        X[5]=cmul(X[5],Er); Er=cmul(Er,E);
        X[6]=cmul(X[6],Er); Er=cmul(Er,E);
        X[7]=cmul(X[7],Er);
        core8i(X);
        buf[bC]=X[0];    buf[bC+8]=X[1];  buf[bC+18]=X[2]; buf[bC+26]=X[3];
        buf[bC+36]=X[4]; buf[bC+44]=X[5]; buf[bC+54]=X[6]; buf[bC+62]=X[7];
    }
    WFENCE();                                  // wave-local

    {
        // pass 3' (H=64) — wave-local
#pragma unroll
        for (int d = 0; d < 8; d++) X[d] = buf[bB + 72 * d];
        float sn, cn; __sincosf((PIF / 256.0f) * (float)j2, &sn, &cn);
        float2 E = make_float2(cn, sn), Er = E;
        X[1]=cmul(X[1],Er); Er=cmul(Er,E);
        X[2]=cmul(X[2],Er); Er=cmul(Er,E);
        X[3]=cmul(X[3],Er); Er=cmul(Er,E);
        X[4]=cmul(X[4],Er); Er=cmul(Er,E);
        X[5]=cmul(X[5],Er); Er=cmul(Er,E);
        X[6]=cmul(X[6],Er); Er=cmul(Er,E);
        X[7]=cmul(X[7],Er);
        core8i(X);
#pragma unroll
        for (int d = 0; d < 8; d++) buf[bB + 72 * d] = X[d];
    }
    __syncthreads();                           // B19 (pass 4' reads across blocks)

    {
        // pass 4' (H=512): final; outputs go straight to global imag planes
#pragma unroll
        for (int d = 0; d < 8; d++) X[d] = buf[bA + 576 * d];
        float sn, cn; __sincosf((PIF / 2048.0f) * (float)tid, &sn, &cn);
        float2 E = make_float2(cn, sn), Er = E;
        X[1]=cmul(X[1],Er); Er=cmul(Er,E);
        X[2]=cmul(X[2],Er); Er=cmul(Er,E);
        X[3]=cmul(X[3],Er); Er=cmul(Er,E);
        X[4]=cmul(X[4],Er); Er=cmul(Er,E);
        X[5]=cmul(X[5],Er); Er=cmul(Er,E);
        X[6]=cmul(X[6],Er); Er=cmul(Er,E);
        X[7]=cmul(X[7],Er);
        core8i(X);
        // X[d] = (Hx[2p], Hx[2p+1]), p = tid + 512d
#pragma unroll
        for (int d = 0; d < 8; d++) {
            int p = tid + 512 * d;
            float2 vv = X[d];
            *(float2*)(g_out + base1 + PP + 2 * p)         = vv;                        // raw imag
            *(float2*)(g_out + base0 + 2 * PP - 2 - 2 * p) = make_float2(vv.y, vv.x);   // flipped imag
        }
    }
}

extern "C" void kernel_launch(void* const* d_in, const int* in_sizes, int n_in,
                              void* d_out, int out_size, void* d_ws, size_t ws_size,
                              hipStream_t stream)
{
    const float* start = (const float*)d_in[0];
    const float* end_  = (const float*)d_in[1];
    const float* stdv  = (const float*)d_in[2];
    const float* lowb  = (const float*)d_in[3];
    const float* upb   = (const float*)d_in[4];
    const int*   win   = (const int*)d_in[5];
    const float* scl   = (const float*)d_in[6];
    const float* noise = (const float*)d_in[7];
    const float* omit  = (const float*)d_in[8];
    const float* ppm   = (const float*)d_in[9];
    const float* ppmr  = (const float*)d_in[10];
    float* out = (float*)d_out;

    hipLaunchKernelGGL(k_all, dim3(NB), dim3(512), 0, stream,
                       start, end_, stdv, lowb, upb, win, scl, noise, omit,
                       ppm, ppmr, out);
}